// Round 5
// baseline (1012.248 us; speedup 1.0000x reference)
//
#include <hip/hip_runtime.h>
#include <hip/hip_bf16.h>
#include <cstddef>

#define B_ 2
#define C_ 16
#define H_ 128
#define W_ 128
#define M_ 9
#define ND_ 9
#define MC_ 144
#define HID_ 18
#define OUT_ 150
#define GOC_ 152          // padded oc stride for G (8B-aligned quads)
#define EPS_ 1e-5f

// ---- workspace layout (float offsets) ----
#define OFF_P     0          // [B][144] pooled means                 (288)
#define OFF_XG    512        // [B][9]  global-attention out          (18)
#define OFF_W1F   1024       // conv1 w, BN1-folded: [mc][kw][kh][kdd][18] (69984)
#define OFF_B1F   71040      // [18]
#define OFF_W2F   71104      // conv2 w, BN2-folded: [c][tap][9]      (4374)
#define OFF_B2F   75520      // [9]
#define OFF_CLWT  75584      // cl_w transposed [mc][150]             (21600)
#define OFF_F     98304      // F[b][m][kdd][h][wpp=130][20pad]       (17,971,200)
#define OFF_HBUF  18069504   // h pre-relu: [b][h][d][w][18]          (5,308,416)
#define OFF_WEI   23377920   // sigmoid attention: [b][h][w][d][9]    (2,654,208)
// G (bf16) overlays F+HBUF: both are dead before k_G runs.
// G[b][h][m][w'][152] = 44,777,472 bf16 = 89.6 MB; ends well before OFF_WEI.
#define OFF_GB_BYTES (98304ull*4ull)

// ---------------- K1: pooled mean of cost volume (global-attn input) ----------
// Split over 8 h-ranges per (b,mc); atomicAdd into P (zeroed by memset).
__global__ __launch_bounds__(256) void k_pool(const float* __restrict__ x,
                                              float* __restrict__ ws) {
  int bid = blockIdx.x;                 // 0..287 = b*144+mc
  int z   = blockIdx.y;                 // 0..7
  int b = bid / MC_, mc = bid % MC_;
  int m = mc / C_, c = mc % C_;
  int sm = m - 4;
  const float* xb = x + (size_t)(b*C_ + c)*H_*W_*M_;
  float acc = 0.f;
  int i0 = z * (H_*W_*ND_/8);
  int i1 = i0 + (H_*W_*ND_/8);
  for (int idx = i0 + (int)threadIdx.x; idx < i1; idx += 256) {
    int w = idx & 127;
    int t = idx >> 7;
    int d = t % 9;
    int h = t / 9;
    int wc = w + (d - 4)*sm;
    if (wc >= 0 && wc < W_) acc += xb[(h*W_ + wc)*M_ + m];
  }
  __shared__ float red[256];
  red[threadIdx.x] = acc;
  __syncthreads();
  for (int s = 128; s > 0; s >>= 1) {
    if ((int)threadIdx.x < s) red[threadIdx.x] += red[threadIdx.x + s];
    __syncthreads();
  }
  if (threadIdx.x == 0)
    atomicAdd(&ws[OFF_P + b*MC_ + mc], red[0] * (1.f/(float)(H_*W_*ND_)));
}

// ---------------- K2: fold BN into conv weights; transpose layouts ------------
__global__ __launch_bounds__(256) void k_repack(
    const float* __restrict__ w1, const float* __restrict__ b1,
    const float* __restrict__ g1, const float* __restrict__ be1,
    const float* __restrict__ m1, const float* __restrict__ v1,
    const float* __restrict__ w2, const float* __restrict__ b2,
    const float* __restrict__ g2, const float* __restrict__ be2,
    const float* __restrict__ m2, const float* __restrict__ v2,
    const float* __restrict__ clw, float* __restrict__ ws) {
  int id = blockIdx.x*256 + threadIdx.x;
  if (id < 69984) {                      // w1f: [mc][kw][kh][kdd][o]
    int o   = id % 18;
    int kdd = (id/18) % 3;
    int kh  = (id/54) % 3;
    int kw  = (id/162) % 3;
    int mc  = id/486;
    float s = g1[o] / sqrtf(v1[o] + EPS_);
    ws[OFF_W1F + id] = w1[(o*MC_ + mc)*27 + kh*9 + kw*3 + kdd] * s;
    return;
  }
  id -= 69984;
  if (id < 18) {
    float s = g1[id]/sqrtf(v1[id]+EPS_);
    ws[OFF_B1F + id] = (b1[id]-m1[id])*s + be1[id];
    return;
  }
  id -= 18;
  if (id < 4374) {                       // w2f: [c][tap][i]
    int i = id % 9, tap = (id/9) % 27, c = id/243;
    float s = g2[i]/sqrtf(v2[i]+EPS_);
    ws[OFF_W2F + id] = w2[(i*HID_ + c)*27 + tap] * s;
    return;
  }
  id -= 4374;
  if (id < 9) {
    float s = g2[id]/sqrtf(v2[id]+EPS_);
    ws[OFF_B2F + id] = (b2[id]-m2[id])*s + be2[id];
    return;
  }
  id -= 9;
  if (id < 21600) {                      // clwT: [mc][oc]
    int oc = id % OUT_, mc = id / OUT_;
    ws[OFF_CLWT + id] = clw[oc*MC_ + mc];
  }
}

// ---------------- K3: global attention branch (1x1x1 volume => center taps) ---
__global__ __launch_bounds__(64) void k_ga(
    const float* __restrict__ gw1, const float* __restrict__ gb1,
    const float* __restrict__ gg1, const float* __restrict__ gbe1,
    const float* __restrict__ gm1, const float* __restrict__ gv1,
    const float* __restrict__ gw2, const float* __restrict__ gb2,
    const float* __restrict__ gg2, const float* __restrict__ gbe2,
    const float* __restrict__ gm2, const float* __restrict__ gv2,
    float* __restrict__ ws) {
  __shared__ float gl[B_*HID_];
  int t = threadIdx.x;
  if (t < B_*HID_) {
    int b = t / HID_, j = t % HID_;
    float acc = gb1[j];
    for (int ch = 0; ch < MC_; ch++)
      acc += gw1[(j*MC_ + ch)*27 + 13] * ws[OFF_P + b*MC_ + ch];
    float s = gg1[j]/sqrtf(gv1[j]+EPS_);
    gl[t] = fmaxf((acc - gm1[j])*s + gbe1[j], 0.f);
  }
  __syncthreads();
  if (t < B_*M_) {
    int b = t / M_, i = t % M_;
    float acc = gb2[i];
    for (int j = 0; j < HID_; j++)
      acc += gw2[(i*HID_ + j)*27 + 13] * gl[b*HID_ + j];
    float s = gg2[i]/sqrtf(gv2[i]+EPS_);
    ws[OFF_XG + b*M_ + i] = (acc - gm2[i])*s + gbe2[i];
  }
}

// ---------------- K4: F[b][m][kdd][h][w''][o] = per-(m,kdd) 2D 3x3 conv of x --
// v4 = v1 structure (trickled scalar stores: measured-clean 70 MB WRITE_SIZE)
// with 2 output rows/block instead of 4: grid 1152 blocks, LDS 33.8 KB ->
// ~4.5 resident blocks/CU (was 2.25) for 2x latency hiding. xt rows padded to
// stride 4 -> aligned float4 reads. v2/v3's end-of-kernel store bursts at
// 1 block/CU caused 5x HBM write amplification - abandoned.
__global__ __launch_bounds__(256) void k_F(const float* __restrict__ x,
                                           float* __restrict__ ws) {
  int h0 = blockIdx.x * 2;
  int m  = blockIdx.y;
  int b  = blockIdx.z;
  __shared__ float xt[C_*132*4];        // [c][col 0..131][row 0..3] 33.8 KB
  for (int e = threadIdx.x; e < C_*132*4; e += 256) {
    int hh = e & 3;
    int cc = (e >> 2) % 132;
    int c  = e / 528;
    int row = h0 - 1 + hh;
    int col = cc - 2;
    float v = 0.f;
    if ((unsigned)row < 128u && (unsigned)col < 128u)
      v = x[(((size_t)(b*C_ + c)*H_ + row)*W_ + col)*M_ + m];
    xt[e] = v;
  }
  __syncthreads();
  const float* w1f = ws + OFF_W1F;
  float* Fb = ws + OFF_F + (size_t)(b*M_ + m)*3*H_*130*20;
  for (int pp = threadIdx.x; pp < 130*18; pp += 256) {
    int o   = pp % 18;
    int wpp = pp / 18;                  // w'' = wpp-1 in [-1,128]
    float acc[3][2] = {};
    for (int c = 0; c < C_; c++) {
      int wb = (m*C_ + c)*486 + o;
      #pragma unroll
      for (int kw = 0; kw < 3; kw++) {
        float4 x4 = *(const float4*)&xt[(c*132 + wpp + kw)*4];
        float xvv[4] = {x4.x, x4.y, x4.z, x4.w};
        const float* wp = w1f + wb + kw*162;
        #pragma unroll
        for (int kh = 0; kh < 3; kh++)
          #pragma unroll
          for (int kdd = 0; kdd < 3; kdd++) {
            float wv = wp[kh*54 + kdd*18];
            acc[kdd][0] += wv * xvv[kh];
            acc[kdd][1] += wv * xvv[kh + 1];
          }
      }
    }
    #pragma unroll
    for (int kdd = 0; kdd < 3; kdd++)
      #pragma unroll
      for (int hh = 0; hh < 2; hh++)
        Fb[(((size_t)kdd*H_ + (h0+hh))*130 + wpp)*20 + o] = acc[kdd][hh];
  }
}

// ---------------- K5: conv1 = gather-sum of F (+edge fix) + BN bias + ReLU ----
// One block per (h,b); 576 threads = 9 waves, wave d = disparity.
// Per m (9 iters): 3 F rows reg-prefetched then LDS (stride-21, conflict-free);
// all 9 d reuse them -> F read exactly once. Edge correction in-block.
__global__ __launch_bounds__(576) void k_comb1(const float* __restrict__ x,
                                               float* __restrict__ ws) {
  const int h = blockIdx.x;
  const int b = blockIdx.y;
  const int t = threadIdx.x;
  const int d    = t >> 6;             // wave id 0..8 = output disparity
  const int lane = t & 63;

  __shared__ float fs[3*2730];         // current-m F rows: [kdd][wpp*21 + o]
  __shared__ float xe[7776];           // [m][edge][dp][kh][c] for edge fix
  __shared__ float corr[9][2][18];

  // ---- per-thread staging slots: 1950 float4s (3 rows x 650) over 576 thr ----
  const int iA = t, iB = t + 576, iC = t + 1152, iD = t + 1728;
  const bool vD = (iD < 1950);
  const int kA = iA/650, rA_ = iA%650;
  const int kB = iB/650, rB_ = iB%650;
  const int kC = iC/650, rC_ = iC%650;
  const int kD = vD ? iD/650 : 0, rD_ = vD ? iD%650 : 0;
  // global float offset within m-slab: kdd*(128*2600) + h*2600 + rem*4
  const int gA = kA*332800 + h*2600 + rA_*4;
  const int gB = kB*332800 + h*2600 + rB_*4;
  const int gC = kC*332800 + h*2600 + rC_*4;
  const int gD = kD*332800 + h*2600 + rD_*4;
  // LDS float offset: kdd*2730 + wpp*21 + j*4   (wpp=rem/5, j=rem%5)
  const int lA = kA*2730 + (rA_/5)*21 + (rA_%5)*4;
  const int lB = kB*2730 + (rB_/5)*21 + (rB_%5)*4;
  const int lC = kC*2730 + (rC_/5)*21 + (rC_%5)*4;
  const int lD = kD*2730 + (rD_/5)*21 + (rD_%5)*4;

  // prefetch m=0 F rows into regs (latency hidden under xe staging + corr)
  size_t mb = (size_t)OFF_F + (size_t)(b*9 + 0)*998400;
  float4 rA = *(const float4*)(ws + mb + gA);
  float4 rB = *(const float4*)(ws + mb + gB);
  float4 rC = *(const float4*)(ws + mb + gC);
  float4 rD = vD ? *(const float4*)(ws + mb + gD) : make_float4(0.f,0.f,0.f,0.f);

  // ---- stage x values needed by the edge correction ----
  for (int e = t; e < 7776; e += 576) {
    int c    = e & 15;
    int kh   = (e >> 4) % 3;
    int dp   = (e / 48) % 9;
    int edge = (e / 432) & 1;
    int m    = e / 864;
    int row = h + kh - 1;
    int col = edge ? 128 + (dp - 4)*(m - 4) : (dp - 4)*(m - 4) - 1;
    float v = 0.f;
    if ((unsigned)row < 128u && (unsigned)col < 128u)
      v = x[(((size_t)(b*C_ + c)*H_ + row)*W_ + col)*M_ + m];
    xe[e] = v;
  }
  __syncthreads();

  // ---- cooperative edge correction: 324 threads, one (d,edge,o) each ----
  if (t < 324) {
    int o    = t % 18;
    int edge = (t / 18) & 1;
    int dd   = t / 36;
    int kwe  = edge ? 2 : 0;
    const float* w1b = ws + OFF_W1F + kwe*162 + o;
    float s = 0.f;
    for (int m = 0; m < 9; m++) {
      #pragma unroll
      for (int kdd = 0; kdd < 3; kdd++) {
        int dp = dd + kdd - 1;
        if (dp < 0 || dp >= 9) continue;
        const float* xp = xe + ((m*2 + edge)*9 + dp)*48;   // [kh][c]
        const float* wp = w1b + m*7776 + kdd*18;
        for (int c = 0; c < 16; c++) {
          #pragma unroll
          for (int kh = 0; kh < 3; kh++)
            s += wp[c*486 + kh*54] * xp[kh*16 + c];
        }
      }
    }
    corr[dd][edge][o] = s;
  }

  float acc0[18], acc1[18];
  #pragma unroll
  for (int o = 0; o < 18; o++) {
    float bz = ws[OFF_B1F + o];
    acc0[o] = bz; acc1[o] = bz;
  }

  __syncthreads();                      // corr done; fs safe to fill

  for (int m = 0; m < 9; m++) {
    // commit prefetched regs -> LDS (stride-21)
    fs[lA+0]=rA.x; fs[lA+1]=rA.y; fs[lA+2]=rA.z; fs[lA+3]=rA.w;
    fs[lB+0]=rB.x; fs[lB+1]=rB.y; fs[lB+2]=rB.z; fs[lB+3]=rB.w;
    fs[lC+0]=rC.x; fs[lC+1]=rC.y; fs[lC+2]=rC.z; fs[lC+3]=rC.w;
    if (vD) { fs[lD+0]=rD.x; fs[lD+1]=rD.y; fs[lD+2]=rD.z; fs[lD+3]=rD.w; }
    // issue next-m loads (hidden under this m's compute)
    if (m < 8) {
      mb = (size_t)OFF_F + (size_t)(b*9 + m + 1)*998400;
      rA = *(const float4*)(ws + mb + gA);
      rB = *(const float4*)(ws + mb + gB);
      rC = *(const float4*)(ws + mb + gC);
      if (vD) rD = *(const float4*)(ws + mb + gD);
    }
    __syncthreads();

    const int sm = m - 4;
    #pragma unroll
    for (int kdd = 0; kdd < 3; kdd++) {
      int dp = d + kdd - 1;
      if (dp >= 0 && dp < 9) {          // wave-uniform
        int shift = (dp - 4)*sm;
        const float* row_ = fs + kdd*2730;
        int wg0 = lane + shift;
        if (wg0 >= -1 && wg0 <= 128) {
          const float* p = row_ + (wg0 + 1)*21;
          #pragma unroll
          for (int o = 0; o < 18; o++) acc0[o] += p[o];
        }
        int wg1 = wg0 + 64;
        if (wg1 >= -1 && wg1 <= 128) {
          const float* p = row_ + (wg1 + 1)*21;
          #pragma unroll
          for (int o = 0; o < 18; o++) acc1[o] += p[o];
        }
      }
    }
    __syncthreads();                    // all waves done before fs overwrite
  }

  if (lane == 0) {
    #pragma unroll
    for (int o = 0; o < 18; o++) acc0[o] -= corr[d][0][o];
  }
  if (lane == 63) {
    #pragma unroll
    for (int o = 0; o < 18; o++) acc1[o] -= corr[d][1][o];
  }

  // store with ReLU, layout [b][h][d][w][18]
  float* hb = ws + OFF_HBUF + ((size_t)((b*H_ + h)*ND_ + d)*W_)*18;
  float2* p0 = (float2*)(hb + (size_t)lane*18);
  float2* p1 = (float2*)(hb + (size_t)(lane + 64)*18);
  #pragma unroll
  for (int q = 0; q < 9; q++) {
    p0[q] = make_float2(fmaxf(acc0[2*q], 0.f), fmaxf(acc0[2*q+1], 0.f));
    p1[q] = make_float2(fmaxf(acc1[2*q], 0.f), fmaxf(acc1[2*q+1], 0.f));
  }
}

// ---------------- K6: conv2 (18->9, 3x3x3) + BN + x_g + sigmoid -> wei --------
__global__ __launch_bounds__(576) void k_conv2(float* __restrict__ ws) {
  int w0 = blockIdx.x * 8;
  int h0 = blockIdx.y * 8;
  int b  = blockIdx.z;
  int t  = threadIdx.x;
  int lh = t / 72;
  int lw = (t / 9) % 8;
  int d  = t % 9;
  __shared__ float ht[9900];            // [hh 10][ww 10][dd 11][cc 9]
  const float* hbuf = ws + OFF_HBUF;
  const float* w2f  = ws + OFF_W2F;
  float acc[9] = {};
  for (int c0 = 0; c0 < 18; c0 += 9) {
    __syncthreads();
    for (int e = t; e < 9900; e += 576) {
      int cc = e % 9;
      int dd = (e/9) % 11;
      int ww = (e/99) % 10;
      int hh = e / 990;
      int gh = h0 - 1 + hh, gw = w0 - 1 + ww, gd = dd - 1;
      float v = 0.f;
      if (gh >= 0 && gh < H_ && gw >= 0 && gw < W_ && gd >= 0 && gd < ND_)
        v = hbuf[(((size_t)(b*H_ + gh)*ND_ + gd)*W_ + gw)*18 + c0 + cc];
      ht[e] = v;
    }
    __syncthreads();
    for (int cc = 0; cc < 9; cc++) {
      #pragma unroll
      for (int kh = 0; kh < 3; kh++)
        #pragma unroll
        for (int kw = 0; kw < 3; kw++)
          #pragma unroll
          for (int kdd = 0; kdd < 3; kdd++) {
            float v = ht[(((lh+kh)*10 + (lw+kw))*11 + (d+kdd))*9 + cc];
            const float* wp = w2f + ((c0+cc)*27 + kh*9 + kw*3 + kdd)*9;
            #pragma unroll
            for (int i = 0; i < 9; i++) acc[i] += wp[i] * v;
          }
    }
  }
  int h = h0 + lh, w = w0 + lw;
  float* wei = ws + OFF_WEI + ((size_t)((b*H_ + h)*W_ + w)*9 + d)*9;
  const float* xg = ws + OFF_XG + b*M_;
  #pragma unroll
  for (int i = 0; i < 9; i++) {
    float y = acc[i] + ws[OFF_B2F + i] + xg[i];
    wei[i] = 1.f / (1.f + expf(-y));
  }
}

// ---------------- K7: G[b][h][m][w'][152] = sum_c clw[oc][mc]*x[c,h,w',m] -----
// x row staged in LDS once; compute with broadcast float4 LDS reads.
__global__ __launch_bounds__(192) void k_G(const float* __restrict__ x,
                                           const float* __restrict__ ws,
                                           __hip_bfloat16* __restrict__ Gb) {
  int h = blockIdx.x, m = blockIdx.y, b = blockIdx.z;
  __shared__ float xs[C_][W_];          // 8 KB
  for (int e = threadIdx.x; e < C_*W_; e += 192) {
    int c = e >> 7, wp = e & 127;
    xs[c][wp] = x[(((size_t)(b*C_ + c)*H_ + h)*W_ + wp)*M_ + m];
  }
  __syncthreads();
  int oc = threadIdx.x;
  if (oc >= GOC_) return;
  __hip_bfloat16* Gr = Gb + ((size_t)(b*H_ + h)*M_ + m)*W_*GOC_;
  if (oc >= OUT_) {                     // zero the pad lanes
    for (int wp = 0; wp < W_; wp++) Gr[wp*GOC_ + oc] = __float2bfloat16(0.f);
    return;
  }
  const float* clwT = ws + OFF_CLWT;
  float wreg[C_];
  #pragma unroll
  for (int c = 0; c < C_; c++) wreg[c] = clwT[(m*C_ + c)*OUT_ + oc];
  for (int wp0 = 0; wp0 < W_; wp0 += 4) {
    float a0 = 0.f, a1 = 0.f, a2 = 0.f, a3 = 0.f;
    #pragma unroll
    for (int c = 0; c < C_; c++) {
      float4 xv = *(const float4*)&xs[c][wp0];
      a0 += wreg[c]*xv.x; a1 += wreg[c]*xv.y;
      a2 += wreg[c]*xv.z; a3 += wreg[c]*xv.w;
    }
    Gr[(wp0+0)*GOC_ + oc] = __float2bfloat16(a0);
    Gr[(wp0+1)*GOC_ + oc] = __float2bfloat16(a1);
    Gr[(wp0+2)*GOC_ + oc] = __float2bfloat16(a2);
    Gr[(wp0+3)*GOC_ + oc] = __float2bfloat16(a3);
  }
}

// ---------------- K8: out = cl_b + sum_m wei[m]*G[h][m][w+s][oc] --------------
__global__ __launch_bounds__(256) void k_last(const float* __restrict__ ws,
                                              const __hip_bfloat16* __restrict__ Gb,
                                              const float* __restrict__ clb,
                                              float* __restrict__ out) {
  int h = blockIdx.y;
  int b = blockIdx.z;
  int idx = blockIdx.x*256 + threadIdx.x;   // 0..4863 = w*38 + ocq
  int w   = idx / 38;
  int ocq = idx % 38;
  int oc0 = ocq * 4;

  float acc[9][4];
  #pragma unroll
  for (int j = 0; j < 4; j++) {
    float cb = (oc0 + j < OUT_) ? clb[oc0 + j] : 0.f;
    #pragma unroll
    for (int d = 0; d < 9; d++) acc[d][j] = cb;
  }

  const float* wv = ws + OFF_WEI + (size_t)((b*H_ + h)*W_ + w)*81;
  const __hip_bfloat16* Gh = Gb + (size_t)(b*H_ + h)*M_*W_*GOC_;
  for (int m = 0; m < 9; m++) {
    int sm = m - 4;
    const __hip_bfloat16* Gm = Gh + (size_t)m*W_*GOC_;
    #pragma unroll
    for (int d = 0; d < 9; d++) {
      int wg = w + (d - 4)*sm;
      if (wg < 0 || wg >= W_) continue;
      ushort4 u = *(const ushort4*)(Gm + wg*GOC_ + oc0);
      float wf = wv[d*9 + m];
      acc[d][0] += wf * __uint_as_float(((unsigned)u.x) << 16);
      acc[d][1] += wf * __uint_as_float(((unsigned)u.y) << 16);
      acc[d][2] += wf * __uint_as_float(((unsigned)u.z) << 16);
      acc[d][3] += wf * __uint_as_float(((unsigned)u.w) << 16);
    }
  }

  #pragma unroll
  for (int j = 0; j < 4; j++) {
    int oc = oc0 + j;
    if (oc >= OUT_) break;
    float* op = out + (((size_t)(b*OUT_ + oc)*H_ + h)*W_ + w)*9;
    #pragma unroll
    for (int d = 0; d < 9; d++) op[d] = acc[d][j];
  }
}

extern "C" void kernel_launch(void* const* d_in, const int* in_sizes, int n_in,
                              void* d_out, int out_size, void* d_ws, size_t ws_size,
                              hipStream_t stream) {
  const float* x       = (const float*)d_in[0];
  const float* la_w1   = (const float*)d_in[1];
  const float* la_b1   = (const float*)d_in[2];
  const float* la_g1   = (const float*)d_in[3];
  const float* la_be1  = (const float*)d_in[4];
  const float* la_m1   = (const float*)d_in[5];
  const float* la_v1   = (const float*)d_in[6];
  const float* la_w2   = (const float*)d_in[7];
  const float* la_b2   = (const float*)d_in[8];
  const float* la_g2   = (const float*)d_in[9];
  const float* la_be2  = (const float*)d_in[10];
  const float* la_m2   = (const float*)d_in[11];
  const float* la_v2   = (const float*)d_in[12];
  const float* ga_w1   = (const float*)d_in[13];
  const float* ga_b1   = (const float*)d_in[14];
  const float* ga_g1   = (const float*)d_in[15];
  const float* ga_be1  = (const float*)d_in[16];
  const float* ga_m1   = (const float*)d_in[17];
  const float* ga_v1   = (const float*)d_in[18];
  const float* ga_w2   = (const float*)d_in[19];
  const float* ga_b2   = (const float*)d_in[20];
  const float* ga_g2   = (const float*)d_in[21];
  const float* ga_be2  = (const float*)d_in[22];
  const float* ga_m2   = (const float*)d_in[23];
  const float* ga_v2   = (const float*)d_in[24];
  const float* cl_w    = (const float*)d_in[25];
  const float* cl_b    = (const float*)d_in[26];

  float* ws = (float*)d_ws;
  __hip_bfloat16* Gb = (__hip_bfloat16*)((char*)d_ws + OFF_GB_BYTES);
  float* out = (float*)d_out;

  hipMemsetAsync(d_ws, 0, MC_*B_*sizeof(float), stream);   // zero P for atomics
  k_pool  <<<dim3(288, 8), 256, 0, stream>>>(x, ws);
  k_repack<<<375, 256, 0, stream>>>(la_w1, la_b1, la_g1, la_be1, la_m1, la_v1,
                                    la_w2, la_b2, la_g2, la_be2, la_m2, la_v2,
                                    cl_w, ws);
  k_ga    <<<1, 64, 0, stream>>>(ga_w1, ga_b1, ga_g1, ga_be1, ga_m1, ga_v1,
                                 ga_w2, ga_b2, ga_g2, ga_be2, ga_m2, ga_v2, ws);
  k_F     <<<dim3(64, 9, 2), 256, 0, stream>>>(x, ws);
  k_comb1 <<<dim3(128, 2), 576, 0, stream>>>(x, ws);
  k_conv2 <<<dim3(16, 16, 2), 576, 0, stream>>>(ws);
  k_G     <<<dim3(128, 9, 2), 192, 0, stream>>>(x, ws, Gb);
  k_last  <<<dim3(19, 128, 2), 256, 0, stream>>>(ws, Gb, cl_b, out);
}

// Round 6
// 915.864 us; speedup vs baseline: 1.1052x; 1.1052x over previous
//
#include <hip/hip_runtime.h>
#include <hip/hip_bf16.h>
#include <cstddef>

#define B_ 2
#define C_ 16
#define H_ 128
#define W_ 128
#define M_ 9
#define ND_ 9
#define MC_ 144
#define HID_ 18
#define OUT_ 150
#define GOC_ 152          // padded oc stride for G (8B-aligned quads)
#define EPS_ 1e-5f

// ---- workspace layout (float offsets) ----
#define OFF_P     0          // [B][144] pooled means                 (288)
#define OFF_XG    512        // [B][9]  global-attention out          (18)
#define OFF_W1F   1024       // conv1 w, BN1-folded: [mc][kw][kh][kdd][18] (69984)
#define OFF_B1F   71040      // [18]
#define OFF_W2F   71104      // conv2 w, BN2-folded: [c][tap][9]      (4374)
#define OFF_B2F   75520      // [9]
#define OFF_CLWT  75584      // cl_w transposed [mc][150]             (21600)
#define OFF_F     98304      // F[b][m][kdd][h][wpp=130][20pad]       (17,971,200)
#define OFF_HBUF  18069504   // h pre-relu: [b][h][d][w][18]          (5,308,416)
#define OFF_WEI   23377920   // sigmoid attention: [b][h][w][d][9]    (2,654,208)
// W1T: conv1 weights re-laid [m][o][c][tap27] for k_F's scalar loads. It lives
// in the TAIL of the HBUF region: k_repack writes it, k_F reads it, and only
// afterwards does k_comb1 overwrite the region with HBUF. (69,984 floats)
#define OFF_W1T   23307936   // = OFF_WEI - 69984
// G (bf16) overlays F+HBUF: both are dead before k_G runs.
// G[b][h][m][w'][152] = 44,777,472 bf16 = 89.6 MB; ends well before OFF_WEI.
#define OFF_GB_BYTES (98304ull*4ull)

// ---------------- K1: pooled mean of cost volume (global-attn input) ----------
// Split over 8 h-ranges per (b,mc); atomicAdd into P (zeroed by memset).
__global__ __launch_bounds__(256) void k_pool(const float* __restrict__ x,
                                              float* __restrict__ ws) {
  int bid = blockIdx.x;                 // 0..287 = b*144+mc
  int z   = blockIdx.y;                 // 0..7
  int b = bid / MC_, mc = bid % MC_;
  int m = mc / C_, c = mc % C_;
  int sm = m - 4;
  const float* xb = x + (size_t)(b*C_ + c)*H_*W_*M_;
  float acc = 0.f;
  int i0 = z * (H_*W_*ND_/8);
  int i1 = i0 + (H_*W_*ND_/8);
  for (int idx = i0 + (int)threadIdx.x; idx < i1; idx += 256) {
    int w = idx & 127;
    int t = idx >> 7;
    int d = t % 9;
    int h = t / 9;
    int wc = w + (d - 4)*sm;
    if (wc >= 0 && wc < W_) acc += xb[(h*W_ + wc)*M_ + m];
  }
  __shared__ float red[256];
  red[threadIdx.x] = acc;
  __syncthreads();
  for (int s = 128; s > 0; s >>= 1) {
    if ((int)threadIdx.x < s) red[threadIdx.x] += red[threadIdx.x + s];
    __syncthreads();
  }
  if (threadIdx.x == 0)
    atomicAdd(&ws[OFF_P + b*MC_ + mc], red[0] * (1.f/(float)(H_*W_*ND_)));
}

// ---------------- K2: fold BN into conv weights; transpose layouts ------------
__global__ __launch_bounds__(256) void k_repack(
    const float* __restrict__ w1, const float* __restrict__ b1,
    const float* __restrict__ g1, const float* __restrict__ be1,
    const float* __restrict__ m1, const float* __restrict__ v1,
    const float* __restrict__ w2, const float* __restrict__ b2,
    const float* __restrict__ g2, const float* __restrict__ be2,
    const float* __restrict__ m2, const float* __restrict__ v2,
    const float* __restrict__ clw, float* __restrict__ ws) {
  int id = blockIdx.x*256 + threadIdx.x;
  if (id < 69984) {                      // w1f: [mc][kw][kh][kdd][o]
    int o   = id % 18;
    int kdd = (id/18) % 3;
    int kh  = (id/54) % 3;
    int kw  = (id/162) % 3;
    int mc  = id/486;
    float s = g1[o] / sqrtf(v1[o] + EPS_);
    ws[OFF_W1F + id] = w1[(o*MC_ + mc)*27 + kh*9 + kw*3 + kdd] * s;
    return;
  }
  id -= 69984;
  if (id < 18) {
    float s = g1[id]/sqrtf(v1[id]+EPS_);
    ws[OFF_B1F + id] = (b1[id]-m1[id])*s + be1[id];
    return;
  }
  id -= 18;
  if (id < 4374) {                       // w2f: [c][tap][i]
    int i = id % 9, tap = (id/9) % 27, c = id/243;
    float s = g2[i]/sqrtf(v2[i]+EPS_);
    ws[OFF_W2F + id] = w2[(i*HID_ + c)*27 + tap] * s;
    return;
  }
  id -= 4374;
  if (id < 9) {
    float s = g2[id]/sqrtf(v2[id]+EPS_);
    ws[OFF_B2F + id] = (b2[id]-m2[id])*s + be2[id];
    return;
  }
  id -= 9;
  if (id < 21600) {                      // clwT: [mc][oc]
    int oc = id % OUT_, mc = id / OUT_;
    ws[OFF_CLWT + id] = clw[oc*MC_ + mc];
    return;
  }
  id -= 21600;
  if (id < 69984) {                      // W1T: [m][o][c][tap27], tap=kw*9+kh*3+kdd
    int tap = id % 27;
    int kw  = tap / 9;
    int kh  = (tap % 9) / 3;
    int kdd = tap % 3;
    int c   = (id/27) % 16;
    int o   = (id/432) % 18;
    int m   = id / 7776;
    float s = g1[o] / sqrtf(v1[o] + EPS_);
    ws[OFF_W1T + id] = w1[(o*MC_ + m*C_ + c)*27 + kh*9 + kw*3 + kdd] * s;
  }
}

// ---------------- K3: global attention branch (1x1x1 volume => center taps) ---
__global__ __launch_bounds__(64) void k_ga(
    const float* __restrict__ gw1, const float* __restrict__ gb1,
    const float* __restrict__ gg1, const float* __restrict__ gbe1,
    const float* __restrict__ gm1, const float* __restrict__ gv1,
    const float* __restrict__ gw2, const float* __restrict__ gb2,
    const float* __restrict__ gg2, const float* __restrict__ gbe2,
    const float* __restrict__ gm2, const float* __restrict__ gv2,
    float* __restrict__ ws) {
  __shared__ float gl[B_*HID_];
  int t = threadIdx.x;
  if (t < B_*HID_) {
    int b = t / HID_, j = t % HID_;
    float acc = gb1[j];
    for (int ch = 0; ch < MC_; ch++)
      acc += gw1[(j*MC_ + ch)*27 + 13] * ws[OFF_P + b*MC_ + ch];
    float s = gg1[j]/sqrtf(gv1[j]+EPS_);
    gl[t] = fmaxf((acc - gm1[j])*s + gbe1[j], 0.f);
  }
  __syncthreads();
  if (t < B_*M_) {
    int b = t / M_, i = t % M_;
    float acc = gb2[i];
    for (int j = 0; j < HID_; j++)
      acc += gw2[(i*HID_ + j)*27 + 13] * gl[b*HID_ + j];
    float s = gg2[i]/sqrtf(gv2[i]+EPS_);
    ws[OFF_XG + b*M_ + i] = (acc - gm2[i])*s + gbe2[i];
  }
}

// ---------------- K4: F[b][m][kdd][h][w''][o] = per-(m,kdd) 2D 3x3 conv of x --
// v5: v1's grid/staging/trickled-store pattern (measured clean: 70 MB WRITE),
// but o is WAVE-UNIFORM (o = wave + 4*oi, lane = wpp): weight loads become
// scalar s_loads of 27 contiguous floats (W1T layout) per (o,c), reused across
// 128 wpp x 12 outputs  -- replaces v1/v4's 432 vector gathers per item
// (582M-1.16G total gathers, the measured bottleneck across R2/R4/R5).
__global__ __launch_bounds__(256) void k_F(const float* __restrict__ x,
                                           float* __restrict__ ws) {
  int h0 = blockIdx.x * 4;
  int m  = blockIdx.y;
  int b  = blockIdx.z;
  const int t = threadIdx.x;
  __shared__ float xt[C_*132*6];        // [c][col 0..131][row 0..5]  50.7 KB
  for (int e = t; e < C_*132*6; e += 256) {
    int hh = e % 6;
    int cc = (e/6) % 132;
    int c  = e / 792;
    int row = h0 - 1 + hh;
    int col = cc - 2;
    float v = 0.f;
    if ((unsigned)row < 128u && (unsigned)col < 128u)
      v = x[(((size_t)(b*C_ + c)*H_ + row)*W_ + col)*M_ + m];
    xt[e] = v;
  }
  __syncthreads();

  const int wave = __builtin_amdgcn_readfirstlane(t >> 6);   // 0..3, SGPR
  const int lane = t & 63;
  const float* w1t = ws + OFF_W1T + (size_t)m*7776;
  float* Fb = ws + OFF_F + (size_t)(b*M_ + m)*3*H_*130*20;

  for (int oi = 0; oi < 5; oi++) {
    int o = wave + oi*4;                // wave-uniform
    if (o >= 18) break;                 // scalar branch (waves 2,3 do 4 o's)
    float acc[3][4][2];
    #pragma unroll
    for (int kdd = 0; kdd < 3; kdd++)
      #pragma unroll
      for (int hh = 0; hh < 4; hh++) {
        acc[kdd][hh][0] = 0.f; acc[kdd][hh][1] = 0.f;
      }
    for (int c = 0; c < C_; c++) {
      const float* wp = w1t + (o*16 + c)*27;   // uniform addr -> s_load
      float wreg[27];
      #pragma unroll
      for (int i = 0; i < 27; i++) wreg[i] = wp[i];
      #pragma unroll
      for (int wq = 0; wq < 2; wq++) {
        int wpp = wq*64 + lane;
        #pragma unroll
        for (int kw = 0; kw < 3; kw++) {
          const float* xb = &xt[(c*132 + wpp + kw)*6];
          float4 lo = *(const float4*)xb;
          float2 hi = *(const float2*)(xb + 4);
          float xv[6] = {lo.x, lo.y, lo.z, lo.w, hi.x, hi.y};
          #pragma unroll
          for (int kh = 0; kh < 3; kh++)
            #pragma unroll
            for (int kdd = 0; kdd < 3; kdd++) {
              float wv = wreg[kw*9 + kh*3 + kdd];
              #pragma unroll
              for (int hh = 0; hh < 4; hh++)
                acc[kdd][hh][wq] += wv * xv[hh + kh];
            }
        }
      }
    }
    #pragma unroll
    for (int wq = 0; wq < 2; wq++) {
      int wpp = wq*64 + lane;
      #pragma unroll
      for (int kdd = 0; kdd < 3; kdd++)
        #pragma unroll
        for (int hh = 0; hh < 4; hh++)
          Fb[(((size_t)kdd*H_ + (h0+hh))*130 + wpp)*20 + o] = acc[kdd][hh][wq];
    }
  }

  // ---- epilogue: wpp = 128,129 (36 items), small per-lane gathers ----
  if (t < 36) {
    int o   = t % 18;
    int wpp = 128 + t/18;
    float acc[3][4];
    #pragma unroll
    for (int kdd = 0; kdd < 3; kdd++)
      #pragma unroll
      for (int hh = 0; hh < 4; hh++) acc[kdd][hh] = 0.f;
    for (int c = 0; c < C_; c++) {
      const float* wp = w1t + (o*16 + c)*27;
      #pragma unroll
      for (int kw = 0; kw < 3; kw++) {
        const float* xb = &xt[(c*132 + wpp + kw)*6];
        float4 lo = *(const float4*)xb;
        float2 hi = *(const float2*)(xb + 4);
        float xv[6] = {lo.x, lo.y, lo.z, lo.w, hi.x, hi.y};
        #pragma unroll
        for (int kh = 0; kh < 3; kh++)
          #pragma unroll
          for (int kdd = 0; kdd < 3; kdd++) {
            float wv = wp[kw*9 + kh*3 + kdd];
            #pragma unroll
            for (int hh = 0; hh < 4; hh++)
              acc[kdd][hh] += wv * xv[hh + kh];
          }
      }
    }
    #pragma unroll
    for (int kdd = 0; kdd < 3; kdd++)
      #pragma unroll
      for (int hh = 0; hh < 4; hh++)
        Fb[(((size_t)kdd*H_ + (h0+hh))*130 + wpp)*20 + o] = acc[kdd][hh];
  }
}

// ---------------- K5: conv1 = gather-sum of F (+edge fix) + BN bias + ReLU ----
// One block per (h,b); 576 threads = 9 waves, wave d = disparity.
// Per m (9 iters): 3 F rows reg-prefetched then LDS (stride-21, conflict-free);
// all 9 d reuse them -> F read exactly once. Edge correction in-block.
__global__ __launch_bounds__(576) void k_comb1(const float* __restrict__ x,
                                               float* __restrict__ ws) {
  const int h = blockIdx.x;
  const int b = blockIdx.y;
  const int t = threadIdx.x;
  const int d    = t >> 6;             // wave id 0..8 = output disparity
  const int lane = t & 63;

  __shared__ float fs[3*2730];         // current-m F rows: [kdd][wpp*21 + o]
  __shared__ float xe[7776];           // [m][edge][dp][kh][c] for edge fix
  __shared__ float corr[9][2][18];

  // ---- per-thread staging slots: 1950 float4s (3 rows x 650) over 576 thr ----
  const int iA = t, iB = t + 576, iC = t + 1152, iD = t + 1728;
  const bool vD = (iD < 1950);
  const int kA = iA/650, rA_ = iA%650;
  const int kB = iB/650, rB_ = iB%650;
  const int kC = iC/650, rC_ = iC%650;
  const int kD = vD ? iD/650 : 0, rD_ = vD ? iD%650 : 0;
  // global float offset within m-slab: kdd*(128*2600) + h*2600 + rem*4
  const int gA = kA*332800 + h*2600 + rA_*4;
  const int gB = kB*332800 + h*2600 + rB_*4;
  const int gC = kC*332800 + h*2600 + rC_*4;
  const int gD = kD*332800 + h*2600 + rD_*4;
  // LDS float offset: kdd*2730 + wpp*21 + j*4   (wpp=rem/5, j=rem%5)
  const int lA = kA*2730 + (rA_/5)*21 + (rA_%5)*4;
  const int lB = kB*2730 + (rB_/5)*21 + (rB_%5)*4;
  const int lC = kC*2730 + (rC_/5)*21 + (rC_%5)*4;
  const int lD = kD*2730 + (rD_/5)*21 + (rD_%5)*4;

  // prefetch m=0 F rows into regs (latency hidden under xe staging + corr)
  size_t mb = (size_t)OFF_F + (size_t)(b*9 + 0)*998400;
  float4 rA = *(const float4*)(ws + mb + gA);
  float4 rB = *(const float4*)(ws + mb + gB);
  float4 rC = *(const float4*)(ws + mb + gC);
  float4 rD = vD ? *(const float4*)(ws + mb + gD) : make_float4(0.f,0.f,0.f,0.f);

  // ---- stage x values needed by the edge correction ----
  for (int e = t; e < 7776; e += 576) {
    int c    = e & 15;
    int kh   = (e >> 4) % 3;
    int dp   = (e / 48) % 9;
    int edge = (e / 432) & 1;
    int m    = e / 864;
    int row = h + kh - 1;
    int col = edge ? 128 + (dp - 4)*(m - 4) : (dp - 4)*(m - 4) - 1;
    float v = 0.f;
    if ((unsigned)row < 128u && (unsigned)col < 128u)
      v = x[(((size_t)(b*C_ + c)*H_ + row)*W_ + col)*M_ + m];
    xe[e] = v;
  }
  __syncthreads();

  // ---- cooperative edge correction: 324 threads, one (d,edge,o) each ----
  if (t < 324) {
    int o    = t % 18;
    int edge = (t / 18) & 1;
    int dd   = t / 36;
    int kwe  = edge ? 2 : 0;
    const float* w1b = ws + OFF_W1F + kwe*162 + o;
    float s = 0.f;
    for (int m = 0; m < 9; m++) {
      #pragma unroll
      for (int kdd = 0; kdd < 3; kdd++) {
        int dp = dd + kdd - 1;
        if (dp < 0 || dp >= 9) continue;
        const float* xp = xe + ((m*2 + edge)*9 + dp)*48;   // [kh][c]
        const float* wp = w1b + m*7776 + kdd*18;
        for (int c = 0; c < 16; c++) {
          #pragma unroll
          for (int kh = 0; kh < 3; kh++)
            s += wp[c*486 + kh*54] * xp[kh*16 + c];
        }
      }
    }
    corr[dd][edge][o] = s;
  }

  float acc0[18], acc1[18];
  #pragma unroll
  for (int o = 0; o < 18; o++) {
    float bz = ws[OFF_B1F + o];
    acc0[o] = bz; acc1[o] = bz;
  }

  __syncthreads();                      // corr done; fs safe to fill

  for (int m = 0; m < 9; m++) {
    // commit prefetched regs -> LDS (stride-21)
    fs[lA+0]=rA.x; fs[lA+1]=rA.y; fs[lA+2]=rA.z; fs[lA+3]=rA.w;
    fs[lB+0]=rB.x; fs[lB+1]=rB.y; fs[lB+2]=rB.z; fs[lB+3]=rB.w;
    fs[lC+0]=rC.x; fs[lC+1]=rC.y; fs[lC+2]=rC.z; fs[lC+3]=rC.w;
    if (vD) { fs[lD+0]=rD.x; fs[lD+1]=rD.y; fs[lD+2]=rD.z; fs[lD+3]=rD.w; }
    // issue next-m loads (hidden under this m's compute)
    if (m < 8) {
      mb = (size_t)OFF_F + (size_t)(b*9 + m + 1)*998400;
      rA = *(const float4*)(ws + mb + gA);
      rB = *(const float4*)(ws + mb + gB);
      rC = *(const float4*)(ws + mb + gC);
      if (vD) rD = *(const float4*)(ws + mb + gD);
    }
    __syncthreads();

    const int sm = m - 4;
    #pragma unroll
    for (int kdd = 0; kdd < 3; kdd++) {
      int dp = d + kdd - 1;
      if (dp >= 0 && dp < 9) {          // wave-uniform
        int shift = (dp - 4)*sm;
        const float* row_ = fs + kdd*2730;
        int wg0 = lane + shift;
        if (wg0 >= -1 && wg0 <= 128) {
          const float* p = row_ + (wg0 + 1)*21;
          #pragma unroll
          for (int o = 0; o < 18; o++) acc0[o] += p[o];
        }
        int wg1 = wg0 + 64;
        if (wg1 >= -1 && wg1 <= 128) {
          const float* p = row_ + (wg1 + 1)*21;
          #pragma unroll
          for (int o = 0; o < 18; o++) acc1[o] += p[o];
        }
      }
    }
    __syncthreads();                    // all waves done before fs overwrite
  }

  if (lane == 0) {
    #pragma unroll
    for (int o = 0; o < 18; o++) acc0[o] -= corr[d][0][o];
  }
  if (lane == 63) {
    #pragma unroll
    for (int o = 0; o < 18; o++) acc1[o] -= corr[d][1][o];
  }

  // store with ReLU, layout [b][h][d][w][18]
  float* hb = ws + OFF_HBUF + ((size_t)((b*H_ + h)*ND_ + d)*W_)*18;
  float2* p0 = (float2*)(hb + (size_t)lane*18);
  float2* p1 = (float2*)(hb + (size_t)(lane + 64)*18);
  #pragma unroll
  for (int q = 0; q < 9; q++) {
    p0[q] = make_float2(fmaxf(acc0[2*q], 0.f), fmaxf(acc0[2*q+1], 0.f));
    p1[q] = make_float2(fmaxf(acc1[2*q], 0.f), fmaxf(acc1[2*q+1], 0.f));
  }
}

// ---------------- K6: conv2 (18->9, 3x3x3) + BN + x_g + sigmoid -> wei --------
__global__ __launch_bounds__(576) void k_conv2(float* __restrict__ ws) {
  int w0 = blockIdx.x * 8;
  int h0 = blockIdx.y * 8;
  int b  = blockIdx.z;
  int t  = threadIdx.x;
  int lh = t / 72;
  int lw = (t / 9) % 8;
  int d  = t % 9;
  __shared__ float ht[9900];            // [hh 10][ww 10][dd 11][cc 9]
  const float* hbuf = ws + OFF_HBUF;
  const float* w2f  = ws + OFF_W2F;
  float acc[9] = {};
  for (int c0 = 0; c0 < 18; c0 += 9) {
    __syncthreads();
    for (int e = t; e < 9900; e += 576) {
      int cc = e % 9;
      int dd = (e/9) % 11;
      int ww = (e/99) % 10;
      int hh = e / 990;
      int gh = h0 - 1 + hh, gw = w0 - 1 + ww, gd = dd - 1;
      float v = 0.f;
      if (gh >= 0 && gh < H_ && gw >= 0 && gw < W_ && gd >= 0 && gd < ND_)
        v = hbuf[(((size_t)(b*H_ + gh)*ND_ + gd)*W_ + gw)*18 + c0 + cc];
      ht[e] = v;
    }
    __syncthreads();
    for (int cc = 0; cc < 9; cc++) {
      #pragma unroll
      for (int kh = 0; kh < 3; kh++)
        #pragma unroll
        for (int kw = 0; kw < 3; kw++)
          #pragma unroll
          for (int kdd = 0; kdd < 3; kdd++) {
            float v = ht[(((lh+kh)*10 + (lw+kw))*11 + (d+kdd))*9 + cc];
            const float* wp = w2f + ((c0+cc)*27 + kh*9 + kw*3 + kdd)*9;
            #pragma unroll
            for (int i = 0; i < 9; i++) acc[i] += wp[i] * v;
          }
    }
  }
  int h = h0 + lh, w = w0 + lw;
  float* wei = ws + OFF_WEI + ((size_t)((b*H_ + h)*W_ + w)*9 + d)*9;
  const float* xg = ws + OFF_XG + b*M_;
  #pragma unroll
  for (int i = 0; i < 9; i++) {
    float y = acc[i] + ws[OFF_B2F + i] + xg[i];
    wei[i] = 1.f / (1.f + expf(-y));
  }
}

// ---------------- K7: G[b][h][m][w'][152] = sum_c clw[oc][mc]*x[c,h,w',m] -----
// x row staged in LDS once; compute with broadcast float4 LDS reads.
__global__ __launch_bounds__(192) void k_G(const float* __restrict__ x,
                                           const float* __restrict__ ws,
                                           __hip_bfloat16* __restrict__ Gb) {
  int h = blockIdx.x, m = blockIdx.y, b = blockIdx.z;
  __shared__ float xs[C_][W_];          // 8 KB
  for (int e = threadIdx.x; e < C_*W_; e += 192) {
    int c = e >> 7, wp = e & 127;
    xs[c][wp] = x[(((size_t)(b*C_ + c)*H_ + h)*W_ + wp)*M_ + m];
  }
  __syncthreads();
  int oc = threadIdx.x;
  if (oc >= GOC_) return;
  __hip_bfloat16* Gr = Gb + ((size_t)(b*H_ + h)*M_ + m)*W_*GOC_;
  if (oc >= OUT_) {                     // zero the pad lanes
    for (int wp = 0; wp < W_; wp++) Gr[wp*GOC_ + oc] = __float2bfloat16(0.f);
    return;
  }
  const float* clwT = ws + OFF_CLWT;
  float wreg[C_];
  #pragma unroll
  for (int c = 0; c < C_; c++) wreg[c] = clwT[(m*C_ + c)*OUT_ + oc];
  for (int wp0 = 0; wp0 < W_; wp0 += 4) {
    float a0 = 0.f, a1 = 0.f, a2 = 0.f, a3 = 0.f;
    #pragma unroll
    for (int c = 0; c < C_; c++) {
      float4 xv = *(const float4*)&xs[c][wp0];
      a0 += wreg[c]*xv.x; a1 += wreg[c]*xv.y;
      a2 += wreg[c]*xv.z; a3 += wreg[c]*xv.w;
    }
    Gr[(wp0+0)*GOC_ + oc] = __float2bfloat16(a0);
    Gr[(wp0+1)*GOC_ + oc] = __float2bfloat16(a1);
    Gr[(wp0+2)*GOC_ + oc] = __float2bfloat16(a2);
    Gr[(wp0+3)*GOC_ + oc] = __float2bfloat16(a3);
  }
}

// ---------------- K8: out = cl_b + sum_m wei[m]*G[h][m][w+s][oc] --------------
__global__ __launch_bounds__(256) void k_last(const float* __restrict__ ws,
                                              const __hip_bfloat16* __restrict__ Gb,
                                              const float* __restrict__ clb,
                                              float* __restrict__ out) {
  int h = blockIdx.y;
  int b = blockIdx.z;
  int idx = blockIdx.x*256 + threadIdx.x;   // 0..4863 = w*38 + ocq
  int w   = idx / 38;
  int ocq = idx % 38;
  int oc0 = ocq * 4;

  float acc[9][4];
  #pragma unroll
  for (int j = 0; j < 4; j++) {
    float cb = (oc0 + j < OUT_) ? clb[oc0 + j] : 0.f;
    #pragma unroll
    for (int d = 0; d < 9; d++) acc[d][j] = cb;
  }

  const float* wv = ws + OFF_WEI + (size_t)((b*H_ + h)*W_ + w)*81;
  const __hip_bfloat16* Gh = Gb + (size_t)(b*H_ + h)*M_*W_*GOC_;
  for (int m = 0; m < 9; m++) {
    int sm = m - 4;
    const __hip_bfloat16* Gm = Gh + (size_t)m*W_*GOC_;
    #pragma unroll
    for (int d = 0; d < 9; d++) {
      int wg = w + (d - 4)*sm;
      if (wg < 0 || wg >= W_) continue;
      ushort4 u = *(const ushort4*)(Gm + wg*GOC_ + oc0);
      float wf = wv[d*9 + m];
      acc[d][0] += wf * __uint_as_float(((unsigned)u.x) << 16);
      acc[d][1] += wf * __uint_as_float(((unsigned)u.y) << 16);
      acc[d][2] += wf * __uint_as_float(((unsigned)u.z) << 16);
      acc[d][3] += wf * __uint_as_float(((unsigned)u.w) << 16);
    }
  }

  #pragma unroll
  for (int j = 0; j < 4; j++) {
    int oc = oc0 + j;
    if (oc >= OUT_) break;
    float* op = out + (((size_t)(b*OUT_ + oc)*H_ + h)*W_ + w)*9;
    #pragma unroll
    for (int d = 0; d < 9; d++) op[d] = acc[d][j];
  }
}

extern "C" void kernel_launch(void* const* d_in, const int* in_sizes, int n_in,
                              void* d_out, int out_size, void* d_ws, size_t ws_size,
                              hipStream_t stream) {
  const float* x       = (const float*)d_in[0];
  const float* la_w1   = (const float*)d_in[1];
  const float* la_b1   = (const float*)d_in[2];
  const float* la_g1   = (const float*)d_in[3];
  const float* la_be1  = (const float*)d_in[4];
  const float* la_m1   = (const float*)d_in[5];
  const float* la_v1   = (const float*)d_in[6];
  const float* la_w2   = (const float*)d_in[7];
  const float* la_b2   = (const float*)d_in[8];
  const float* la_g2   = (const float*)d_in[9];
  const float* la_be2  = (const float*)d_in[10];
  const float* la_m2   = (const float*)d_in[11];
  const float* la_v2   = (const float*)d_in[12];
  const float* ga_w1   = (const float*)d_in[13];
  const float* ga_b1   = (const float*)d_in[14];
  const float* ga_g1   = (const float*)d_in[15];
  const float* ga_be1  = (const float*)d_in[16];
  const float* ga_m1   = (const float*)d_in[17];
  const float* ga_v1   = (const float*)d_in[18];
  const float* ga_w2   = (const float*)d_in[19];
  const float* ga_b2   = (const float*)d_in[20];
  const float* ga_g2   = (const float*)d_in[21];
  const float* ga_be2  = (const float*)d_in[22];
  const float* ga_m2   = (const float*)d_in[23];
  const float* ga_v2   = (const float*)d_in[24];
  const float* cl_w    = (const float*)d_in[25];
  const float* cl_b    = (const float*)d_in[26];

  float* ws = (float*)d_ws;
  __hip_bfloat16* Gb = (__hip_bfloat16*)((char*)d_ws + OFF_GB_BYTES);
  float* out = (float*)d_out;

  hipMemsetAsync(d_ws, 0, MC_*B_*sizeof(float), stream);   // zero P for atomics
  k_pool  <<<dim3(288, 8), 256, 0, stream>>>(x, ws);
  k_repack<<<649, 256, 0, stream>>>(la_w1, la_b1, la_g1, la_be1, la_m1, la_v1,
                                    la_w2, la_b2, la_g2, la_be2, la_m2, la_v2,
                                    cl_w, ws);
  k_ga    <<<1, 64, 0, stream>>>(ga_w1, ga_b1, ga_g1, ga_be1, ga_m1, ga_v1,
                                 ga_w2, ga_b2, ga_g2, ga_be2, ga_m2, ga_v2, ws);
  k_F     <<<dim3(32, 9, 2), 256, 0, stream>>>(x, ws);
  k_comb1 <<<dim3(128, 2), 576, 0, stream>>>(x, ws);
  k_conv2 <<<dim3(16, 16, 2), 576, 0, stream>>>(ws);
  k_G     <<<dim3(128, 9, 2), 192, 0, stream>>>(x, ws, Gb);
  k_last  <<<dim3(19, 128, 2), 256, 0, stream>>>(ws, Gb, cl_b, out);
}

// Round 7
// 835.433 us; speedup vs baseline: 1.2116x; 1.0963x over previous
//
#include <hip/hip_runtime.h>
#include <hip/hip_bf16.h>
#include <cstddef>

#define B_ 2
#define C_ 16
#define H_ 128
#define W_ 128
#define M_ 9
#define ND_ 9
#define MC_ 144
#define HID_ 18
#define OUT_ 150
#define GOC_ 152          // padded oc stride for G (8B-aligned quads)
#define EPS_ 1e-5f

// ---- workspace layout (float offsets) ----
#define OFF_P     0          // [B][144] pooled means                 (288)
#define OFF_XG    512        // [B][9]  global-attention out          (18)
#define OFF_W1F   1024       // conv1 w, BN1-folded: [mc][kw][kh][kdd][18] (69984)
#define OFF_B1F   71040      // [18]
#define OFF_W2F   71104      // conv2 w, BN2-folded: [c][tap][9]      (4374)
#define OFF_B2F   75520      // [9]
#define OFF_CLWT  75584      // cl_w transposed [mc][150]             (21600)
#define OFF_F     98304      // F'[b][m][kdd][o][h][wpp132]           (16,422,912)
#define FSLAB_    912384     // per-(b,m) slab = 3*18*128*132
#define OFF_HBUF  18069504   // h pre-relu: [b][h][d][w][18]          (5,308,416)
#define OFF_WEI   23377920   // sigmoid attention: [b][h][w][d][9]    (2,654,208)
// W1T: conv1 weights re-laid [m][o][c][tap27] for k_F's scalar loads. It lives
// in the TAIL of the HBUF region: k_repack writes it, k_F reads it, and only
// afterwards does k_comb1 overwrite the region with HBUF. (69,984 floats)
#define OFF_W1T   23307936   // = OFF_WEI - 69984
// G (bf16) overlays F+HBUF: both are dead before k_G runs.
// G[b][h][m][w'][152] = 44,777,472 bf16 = 89.6 MB; ends well before OFF_WEI.
#define OFF_GB_BYTES (98304ull*4ull)

// ---------------- K1: pooled mean of cost volume (global-attn input) ----------
// Split over 8 h-ranges per (b,mc); atomicAdd into P (zeroed by memset).
__global__ __launch_bounds__(256) void k_pool(const float* __restrict__ x,
                                              float* __restrict__ ws) {
  int bid = blockIdx.x;                 // 0..287 = b*144+mc
  int z   = blockIdx.y;                 // 0..7
  int b = bid / MC_, mc = bid % MC_;
  int m = mc / C_, c = mc % C_;
  int sm = m - 4;
  const float* xb = x + (size_t)(b*C_ + c)*H_*W_*M_;
  float acc = 0.f;
  int i0 = z * (H_*W_*ND_/8);
  int i1 = i0 + (H_*W_*ND_/8);
  for (int idx = i0 + (int)threadIdx.x; idx < i1; idx += 256) {
    int w = idx & 127;
    int t = idx >> 7;
    int d = t % 9;
    int h = t / 9;
    int wc = w + (d - 4)*sm;
    if (wc >= 0 && wc < W_) acc += xb[(h*W_ + wc)*M_ + m];
  }
  __shared__ float red[256];
  red[threadIdx.x] = acc;
  __syncthreads();
  for (int s = 128; s > 0; s >>= 1) {
    if ((int)threadIdx.x < s) red[threadIdx.x] += red[threadIdx.x + s];
    __syncthreads();
  }
  if (threadIdx.x == 0)
    atomicAdd(&ws[OFF_P + b*MC_ + mc], red[0] * (1.f/(float)(H_*W_*ND_)));
}

// ---------------- K2: fold BN into conv weights; transpose layouts ------------
__global__ __launch_bounds__(256) void k_repack(
    const float* __restrict__ w1, const float* __restrict__ b1,
    const float* __restrict__ g1, const float* __restrict__ be1,
    const float* __restrict__ m1, const float* __restrict__ v1,
    const float* __restrict__ w2, const float* __restrict__ b2,
    const float* __restrict__ g2, const float* __restrict__ be2,
    const float* __restrict__ m2, const float* __restrict__ v2,
    const float* __restrict__ clw, float* __restrict__ ws) {
  int id = blockIdx.x*256 + threadIdx.x;
  if (id < 69984) {                      // w1f: [mc][kw][kh][kdd][o]
    int o   = id % 18;
    int kdd = (id/18) % 3;
    int kh  = (id/54) % 3;
    int kw  = (id/162) % 3;
    int mc  = id/486;
    float s = g1[o] / sqrtf(v1[o] + EPS_);
    ws[OFF_W1F + id] = w1[(o*MC_ + mc)*27 + kh*9 + kw*3 + kdd] * s;
    return;
  }
  id -= 69984;
  if (id < 18) {
    float s = g1[id]/sqrtf(v1[id]+EPS_);
    ws[OFF_B1F + id] = (b1[id]-m1[id])*s + be1[id];
    return;
  }
  id -= 18;
  if (id < 4374) {                       // w2f: [c][tap][i]
    int i = id % 9, tap = (id/9) % 27, c = id/243;
    float s = g2[i]/sqrtf(v2[i]+EPS_);
    ws[OFF_W2F + id] = w2[(i*HID_ + c)*27 + tap] * s;
    return;
  }
  id -= 4374;
  if (id < 9) {
    float s = g2[id]/sqrtf(v2[id]+EPS_);
    ws[OFF_B2F + id] = (b2[id]-m2[id])*s + be2[id];
    return;
  }
  id -= 9;
  if (id < 21600) {                      // clwT: [mc][oc]
    int oc = id % OUT_, mc = id / OUT_;
    ws[OFF_CLWT + id] = clw[oc*MC_ + mc];
    return;
  }
  id -= 21600;
  if (id < 69984) {                      // W1T: [m][o][c][tap27], tap=kw*9+kh*3+kdd
    int tap = id % 27;
    int kw  = tap / 9;
    int kh  = (tap % 9) / 3;
    int kdd = tap % 3;
    int c   = (id/27) % 16;
    int o   = (id/432) % 18;
    int m   = id / 7776;
    float s = g1[o] / sqrtf(v1[o] + EPS_);
    ws[OFF_W1T + id] = w1[(o*MC_ + m*C_ + c)*27 + kh*9 + kw*3 + kdd] * s;
  }
}

// ---------------- K3: global attention branch (1x1x1 volume => center taps) ---
__global__ __launch_bounds__(64) void k_ga(
    const float* __restrict__ gw1, const float* __restrict__ gb1,
    const float* __restrict__ gg1, const float* __restrict__ gbe1,
    const float* __restrict__ gm1, const float* __restrict__ gv1,
    const float* __restrict__ gw2, const float* __restrict__ gb2,
    const float* __restrict__ gg2, const float* __restrict__ gbe2,
    const float* __restrict__ gm2, const float* __restrict__ gv2,
    float* __restrict__ ws) {
  __shared__ float gl[B_*HID_];
  int t = threadIdx.x;
  if (t < B_*HID_) {
    int b = t / HID_, j = t % HID_;
    float acc = gb1[j];
    for (int ch = 0; ch < MC_; ch++)
      acc += gw1[(j*MC_ + ch)*27 + 13] * ws[OFF_P + b*MC_ + ch];
    float s = gg1[j]/sqrtf(gv1[j]+EPS_);
    gl[t] = fmaxf((acc - gm1[j])*s + gbe1[j], 0.f);
  }
  __syncthreads();
  if (t < B_*M_) {
    int b = t / M_, i = t % M_;
    float acc = gb2[i];
    for (int j = 0; j < HID_; j++)
      acc += gw2[(i*HID_ + j)*27 + 13] * gl[b*HID_ + j];
    float s = gg2[i]/sqrtf(gv2[i]+EPS_);
    ws[OFF_XG + b*M_ + i] = (acc - gm2[i])*s + gbe2[i];
  }
}

// ---------------- K4: F'[b][m][kdd][o][h][wpp] = per-(m,kdd) 2D 3x3 conv of x -
// v6 = v5's compute (wave-uniform o, scalar s_load weights from W1T; the 1.6x
// win) + o-MAJOR F layout so the natural store pattern (lane = wpp, fixed o)
// is 256B-contiguous per wave-store instruction -- the v1/v4-verified-clean
// shape. v5's lane-scattered 4B stores at 80B stride partially dirtied lines
// at 18 different timepoints -> 5.2x HBM write amplification.
__global__ __launch_bounds__(256) void k_F(const float* __restrict__ x,
                                           float* __restrict__ ws) {
  int h0 = blockIdx.x * 4;
  int m  = blockIdx.y;
  int b  = blockIdx.z;
  const int t = threadIdx.x;
  __shared__ float xt[C_*132*6];        // [c][col 0..131][row 0..5]  50.7 KB
  for (int e = t; e < C_*132*6; e += 256) {
    int hh = e % 6;
    int cc = (e/6) % 132;
    int c  = e / 792;
    int row = h0 - 1 + hh;
    int col = cc - 2;
    float v = 0.f;
    if ((unsigned)row < 128u && (unsigned)col < 128u)
      v = x[(((size_t)(b*C_ + c)*H_ + row)*W_ + col)*M_ + m];
    xt[e] = v;
  }
  __syncthreads();

  const int wave = __builtin_amdgcn_readfirstlane(t >> 6);   // 0..3, SGPR
  const int lane = t & 63;
  const float* w1t = ws + OFF_W1T + (size_t)m*7776;
  float* Fb = ws + OFF_F + (size_t)(b*M_ + m)*FSLAB_;

  for (int oi = 0; oi < 5; oi++) {
    int o = wave + oi*4;                // wave-uniform
    if (o >= 18) break;                 // scalar branch (waves 2,3 do 4 o's)
    float acc[3][4][2];
    #pragma unroll
    for (int kdd = 0; kdd < 3; kdd++)
      #pragma unroll
      for (int hh = 0; hh < 4; hh++) {
        acc[kdd][hh][0] = 0.f; acc[kdd][hh][1] = 0.f;
      }
    for (int c = 0; c < C_; c++) {
      const float* wp = w1t + (o*16 + c)*27;   // uniform addr -> s_load
      float wreg[27];
      #pragma unroll
      for (int i = 0; i < 27; i++) wreg[i] = wp[i];
      #pragma unroll
      for (int wq = 0; wq < 2; wq++) {
        int wpp = wq*64 + lane;
        #pragma unroll
        for (int kw = 0; kw < 3; kw++) {
          const float* xb = &xt[(c*132 + wpp + kw)*6];
          float4 lo = *(const float4*)xb;
          float2 hi = *(const float2*)(xb + 4);
          float xv[6] = {lo.x, lo.y, lo.z, lo.w, hi.x, hi.y};
          #pragma unroll
          for (int kh = 0; kh < 3; kh++)
            #pragma unroll
            for (int kdd = 0; kdd < 3; kdd++) {
              float wv = wreg[kw*9 + kh*3 + kdd];
              #pragma unroll
              for (int hh = 0; hh < 4; hh++)
                acc[kdd][hh][wq] += wv * xv[hh + kh];
            }
        }
      }
    }
    #pragma unroll
    for (int wq = 0; wq < 2; wq++) {
      int wpp = wq*64 + lane;
      #pragma unroll
      for (int kdd = 0; kdd < 3; kdd++)
        #pragma unroll
        for (int hh = 0; hh < 4; hh++)
          Fb[((size_t)(kdd*18 + o)*H_ + (h0+hh))*132 + wpp] = acc[kdd][hh][wq];
    }
  }

  // ---- epilogue: wpp = 128,129 (36 items), small per-lane scatter (~1 MB) ----
  if (t < 36) {
    int o   = t % 18;
    int wpp = 128 + t/18;
    float acc[3][4];
    #pragma unroll
    for (int kdd = 0; kdd < 3; kdd++)
      #pragma unroll
      for (int hh = 0; hh < 4; hh++) acc[kdd][hh] = 0.f;
    for (int c = 0; c < C_; c++) {
      const float* wp = w1t + (o*16 + c)*27;
      #pragma unroll
      for (int kw = 0; kw < 3; kw++) {
        const float* xb = &xt[(c*132 + wpp + kw)*6];
        float4 lo = *(const float4*)xb;
        float2 hi = *(const float2*)(xb + 4);
        float xv[6] = {lo.x, lo.y, lo.z, lo.w, hi.x, hi.y};
        #pragma unroll
        for (int kh = 0; kh < 3; kh++)
          #pragma unroll
          for (int kdd = 0; kdd < 3; kdd++) {
            float wv = wp[kw*9 + kh*3 + kdd];
            #pragma unroll
            for (int hh = 0; hh < 4; hh++)
              acc[kdd][hh] += wv * xv[hh + kh];
          }
      }
    }
    #pragma unroll
    for (int kdd = 0; kdd < 3; kdd++)
      #pragma unroll
      for (int hh = 0; hh < 4; hh++)
        Fb[((size_t)(kdd*18 + o)*H_ + (h0+hh))*132 + wpp] = acc[kdd][hh];
  }
}

// ---------------- K5: conv1 = gather-sum of F' (+edge fix) + BN bias + ReLU ---
// One block per (h,b); 576 threads = 9 waves, wave d = disparity.
// Per m (9 iters): the (kdd,o) rows of F' for this h are reg-prefetched then
// written to LDS as fs[kdd][wpp*21 + o] (stride-21, conflict-free gather);
// all 9 d reuse them -> F' read exactly once. Edge correction in-block.
#define SLAB21_ 2772          // 132*21 floats per kdd slab in LDS
__global__ __launch_bounds__(576) void k_comb1(const float* __restrict__ x,
                                               float* __restrict__ ws) {
  const int h = blockIdx.x;
  const int b = blockIdx.y;
  const int t = threadIdx.x;
  const int d    = t >> 6;             // wave id 0..8 = output disparity
  const int lane = t & 63;

  __shared__ float fs[3*SLAB21_];      // current-m F rows: [kdd][wpp*21 + o]
  __shared__ float xe[7776];           // [m][edge][dp][kh][c] for edge fix
  __shared__ float corr[9][2][18];

  // ---- staging slots: 1782 float4s = 3 kdd x 18 o x 33 q, over 576 thr ------
  // slot i: kdd=i/594, o=(i%594)/33, q=(i%594)%33
  // global float off (within (b,m) slab): ((kdd*18+o)*128 + h)*132 + q*4
  // LDS float off: kdd*2772 + (q*4+j)*21 + o   (j=0..3)
  const int iA = t, iB = t + 576, iC = t + 1152;   // < 1728, always valid
  const bool vD = (t < 54);
  const int iD = 1728 + t;
  const int kA = iA/594, rA_ = iA%594, oA = rA_/33, qA = rA_%33;
  const int kB = iB/594, rB_ = iB%594, oB = rB_/33, qB = rB_%33;
  const int kC = iC/594, rC_ = iC%594, oC = rC_/33, qC = rC_%33;
  const int kD = vD ? iD/594 : 0, rD_ = vD ? iD%594 : 0, oD = rD_/33, qD = rD_%33;
  const int gA = ((kA*18 + oA)*H_ + h)*132 + qA*4;
  const int gB = ((kB*18 + oB)*H_ + h)*132 + qB*4;
  const int gC = ((kC*18 + oC)*H_ + h)*132 + qC*4;
  const int gD = ((kD*18 + oD)*H_ + h)*132 + qD*4;
  const int lA = kA*SLAB21_ + qA*84 + oA;
  const int lB = kB*SLAB21_ + qB*84 + oB;
  const int lC = kC*SLAB21_ + qC*84 + oC;
  const int lD = kD*SLAB21_ + qD*84 + oD;

  // prefetch m=0 F rows into regs (latency hidden under xe staging + corr)
  size_t mb = (size_t)OFF_F + (size_t)(b*9 + 0)*FSLAB_;
  float4 rA = *(const float4*)(ws + mb + gA);
  float4 rB = *(const float4*)(ws + mb + gB);
  float4 rC = *(const float4*)(ws + mb + gC);
  float4 rD = vD ? *(const float4*)(ws + mb + gD) : make_float4(0.f,0.f,0.f,0.f);

  // ---- stage x values needed by the edge correction ----
  for (int e = t; e < 7776; e += 576) {
    int c    = e & 15;
    int kh   = (e >> 4) % 3;
    int dp   = (e / 48) % 9;
    int edge = (e / 432) & 1;
    int m    = e / 864;
    int row = h + kh - 1;
    int col = edge ? 128 + (dp - 4)*(m - 4) : (dp - 4)*(m - 4) - 1;
    float v = 0.f;
    if ((unsigned)row < 128u && (unsigned)col < 128u)
      v = x[(((size_t)(b*C_ + c)*H_ + row)*W_ + col)*M_ + m];
    xe[e] = v;
  }
  __syncthreads();

  // ---- cooperative edge correction: 324 threads, one (d,edge,o) each ----
  if (t < 324) {
    int o    = t % 18;
    int edge = (t / 18) & 1;
    int dd   = t / 36;
    int kwe  = edge ? 2 : 0;
    const float* w1b = ws + OFF_W1F + kwe*162 + o;
    float s = 0.f;
    for (int m = 0; m < 9; m++) {
      #pragma unroll
      for (int kdd = 0; kdd < 3; kdd++) {
        int dp = dd + kdd - 1;
        if (dp < 0 || dp >= 9) continue;
        const float* xp = xe + ((m*2 + edge)*9 + dp)*48;   // [kh][c]
        const float* wp = w1b + m*7776 + kdd*18;
        for (int c = 0; c < 16; c++) {
          #pragma unroll
          for (int kh = 0; kh < 3; kh++)
            s += wp[c*486 + kh*54] * xp[kh*16 + c];
        }
      }
    }
    corr[dd][edge][o] = s;
  }

  float acc0[18], acc1[18];
  #pragma unroll
  for (int o = 0; o < 18; o++) {
    float bz = ws[OFF_B1F + o];
    acc0[o] = bz; acc1[o] = bz;
  }

  __syncthreads();                      // corr done; fs safe to fill

  for (int m = 0; m < 9; m++) {
    // commit prefetched regs -> LDS (stride-21 transpose)
    fs[lA+0]=rA.x; fs[lA+21]=rA.y; fs[lA+42]=rA.z; fs[lA+63]=rA.w;
    fs[lB+0]=rB.x; fs[lB+21]=rB.y; fs[lB+42]=rB.z; fs[lB+63]=rB.w;
    fs[lC+0]=rC.x; fs[lC+21]=rC.y; fs[lC+42]=rC.z; fs[lC+63]=rC.w;
    if (vD) { fs[lD+0]=rD.x; fs[lD+21]=rD.y; fs[lD+42]=rD.z; fs[lD+63]=rD.w; }
    // issue next-m loads (hidden under this m's compute)
    if (m < 8) {
      mb = (size_t)OFF_F + (size_t)(b*9 + m + 1)*FSLAB_;
      rA = *(const float4*)(ws + mb + gA);
      rB = *(const float4*)(ws + mb + gB);
      rC = *(const float4*)(ws + mb + gC);
      if (vD) rD = *(const float4*)(ws + mb + gD);
    }
    __syncthreads();

    const int sm = m - 4;
    #pragma unroll
    for (int kdd = 0; kdd < 3; kdd++) {
      int dp = d + kdd - 1;
      if (dp >= 0 && dp < 9) {          // wave-uniform
        int shift = (dp - 4)*sm;
        const float* row_ = fs + kdd*SLAB21_;
        int wg0 = lane + shift;
        if (wg0 >= -1 && wg0 <= 128) {
          const float* p = row_ + (wg0 + 1)*21;
          #pragma unroll
          for (int o = 0; o < 18; o++) acc0[o] += p[o];
        }
        int wg1 = wg0 + 64;
        if (wg1 >= -1 && wg1 <= 128) {
          const float* p = row_ + (wg1 + 1)*21;
          #pragma unroll
          for (int o = 0; o < 18; o++) acc1[o] += p[o];
        }
      }
    }
    __syncthreads();                    // all waves done before fs overwrite
  }

  if (lane == 0) {
    #pragma unroll
    for (int o = 0; o < 18; o++) acc0[o] -= corr[d][0][o];
  }
  if (lane == 63) {
    #pragma unroll
    for (int o = 0; o < 18; o++) acc1[o] -= corr[d][1][o];
  }

  // store with ReLU, layout [b][h][d][w][18]
  float* hb = ws + OFF_HBUF + ((size_t)((b*H_ + h)*ND_ + d)*W_)*18;
  float2* p0 = (float2*)(hb + (size_t)lane*18);
  float2* p1 = (float2*)(hb + (size_t)(lane + 64)*18);
  #pragma unroll
  for (int q = 0; q < 9; q++) {
    p0[q] = make_float2(fmaxf(acc0[2*q], 0.f), fmaxf(acc0[2*q+1], 0.f));
    p1[q] = make_float2(fmaxf(acc1[2*q], 0.f), fmaxf(acc1[2*q+1], 0.f));
  }
}

// ---------------- K6: conv2 (18->9, 3x3x3) + BN + x_g + sigmoid -> wei --------
__global__ __launch_bounds__(576) void k_conv2(float* __restrict__ ws) {
  int w0 = blockIdx.x * 8;
  int h0 = blockIdx.y * 8;
  int b  = blockIdx.z;
  int t  = threadIdx.x;
  int lh = t / 72;
  int lw = (t / 9) % 8;
  int d  = t % 9;
  __shared__ float ht[9900];            // [hh 10][ww 10][dd 11][cc 9]
  const float* hbuf = ws + OFF_HBUF;
  const float* w2f  = ws + OFF_W2F;
  float acc[9] = {};
  for (int c0 = 0; c0 < 18; c0 += 9) {
    __syncthreads();
    for (int e = t; e < 9900; e += 576) {
      int cc = e % 9;
      int dd = (e/9) % 11;
      int ww = (e/99) % 10;
      int hh = e / 990;
      int gh = h0 - 1 + hh, gw = w0 - 1 + ww, gd = dd - 1;
      float v = 0.f;
      if (gh >= 0 && gh < H_ && gw >= 0 && gw < W_ && gd >= 0 && gd < ND_)
        v = hbuf[(((size_t)(b*H_ + gh)*ND_ + gd)*W_ + gw)*18 + c0 + cc];
      ht[e] = v;
    }
    __syncthreads();
    for (int cc = 0; cc < 9; cc++) {
      #pragma unroll
      for (int kh = 0; kh < 3; kh++)
        #pragma unroll
        for (int kw = 0; kw < 3; kw++)
          #pragma unroll
          for (int kdd = 0; kdd < 3; kdd++) {
            float v = ht[(((lh+kh)*10 + (lw+kw))*11 + (d+kdd))*9 + cc];
            const float* wp = w2f + ((c0+cc)*27 + kh*9 + kw*3 + kdd)*9;
            #pragma unroll
            for (int i = 0; i < 9; i++) acc[i] += wp[i] * v;
          }
    }
  }
  int h = h0 + lh, w = w0 + lw;
  float* wei = ws + OFF_WEI + ((size_t)((b*H_ + h)*W_ + w)*9 + d)*9;
  const float* xg = ws + OFF_XG + b*M_;
  #pragma unroll
  for (int i = 0; i < 9; i++) {
    float y = acc[i] + ws[OFF_B2F + i] + xg[i];
    wei[i] = 1.f / (1.f + expf(-y));
  }
}

// ---------------- K7: G[b][h][m][w'][152] = sum_c clw[oc][mc]*x[c,h,w',m] -----
// x row staged in LDS once; compute with broadcast float4 LDS reads.
__global__ __launch_bounds__(192) void k_G(const float* __restrict__ x,
                                           const float* __restrict__ ws,
                                           __hip_bfloat16* __restrict__ Gb) {
  int h = blockIdx.x, m = blockIdx.y, b = blockIdx.z;
  __shared__ float xs[C_][W_];          // 8 KB
  for (int e = threadIdx.x; e < C_*W_; e += 192) {
    int c = e >> 7, wp = e & 127;
    xs[c][wp] = x[(((size_t)(b*C_ + c)*H_ + h)*W_ + wp)*M_ + m];
  }
  __syncthreads();
  int oc = threadIdx.x;
  if (oc >= GOC_) return;
  __hip_bfloat16* Gr = Gb + ((size_t)(b*H_ + h)*M_ + m)*W_*GOC_;
  if (oc >= OUT_) {                     // zero the pad lanes
    for (int wp = 0; wp < W_; wp++) Gr[wp*GOC_ + oc] = __float2bfloat16(0.f);
    return;
  }
  const float* clwT = ws + OFF_CLWT;
  float wreg[C_];
  #pragma unroll
  for (int c = 0; c < C_; c++) wreg[c] = clwT[(m*C_ + c)*OUT_ + oc];
  for (int wp0 = 0; wp0 < W_; wp0 += 4) {
    float a0 = 0.f, a1 = 0.f, a2 = 0.f, a3 = 0.f;
    #pragma unroll
    for (int c = 0; c < C_; c++) {
      float4 xv = *(const float4*)&xs[c][wp0];
      a0 += wreg[c]*xv.x; a1 += wreg[c]*xv.y;
      a2 += wreg[c]*xv.z; a3 += wreg[c]*xv.w;
    }
    Gr[(wp0+0)*GOC_ + oc] = __float2bfloat16(a0);
    Gr[(wp0+1)*GOC_ + oc] = __float2bfloat16(a1);
    Gr[(wp0+2)*GOC_ + oc] = __float2bfloat16(a2);
    Gr[(wp0+3)*GOC_ + oc] = __float2bfloat16(a3);
  }
}

// ---------------- K8: out = cl_b + sum_m wei[m]*G[h][m][w+s][oc] --------------
__global__ __launch_bounds__(256) void k_last(const float* __restrict__ ws,
                                              const __hip_bfloat16* __restrict__ Gb,
                                              const float* __restrict__ clb,
                                              float* __restrict__ out) {
  int h = blockIdx.y;
  int b = blockIdx.z;
  int idx = blockIdx.x*256 + threadIdx.x;   // 0..4863 = w*38 + ocq
  int w   = idx / 38;
  int ocq = idx % 38;
  int oc0 = ocq * 4;

  float acc[9][4];
  #pragma unroll
  for (int j = 0; j < 4; j++) {
    float cb = (oc0 + j < OUT_) ? clb[oc0 + j] : 0.f;
    #pragma unroll
    for (int d = 0; d < 9; d++) acc[d][j] = cb;
  }

  const float* wv = ws + OFF_WEI + (size_t)((b*H_ + h)*W_ + w)*81;
  const __hip_bfloat16* Gh = Gb + (size_t)(b*H_ + h)*M_*W_*GOC_;
  for (int m = 0; m < 9; m++) {
    int sm = m - 4;
    const __hip_bfloat16* Gm = Gh + (size_t)m*W_*GOC_;
    #pragma unroll
    for (int d = 0; d < 9; d++) {
      int wg = w + (d - 4)*sm;
      if (wg < 0 || wg >= W_) continue;
      ushort4 u = *(const ushort4*)(Gm + wg*GOC_ + oc0);
      float wf = wv[d*9 + m];
      acc[d][0] += wf * __uint_as_float(((unsigned)u.x) << 16);
      acc[d][1] += wf * __uint_as_float(((unsigned)u.y) << 16);
      acc[d][2] += wf * __uint_as_float(((unsigned)u.z) << 16);
      acc[d][3] += wf * __uint_as_float(((unsigned)u.w) << 16);
    }
  }

  #pragma unroll
  for (int j = 0; j < 4; j++) {
    int oc = oc0 + j;
    if (oc >= OUT_) break;
    float* op = out + (((size_t)(b*OUT_ + oc)*H_ + h)*W_ + w)*9;
    #pragma unroll
    for (int d = 0; d < 9; d++) op[d] = acc[d][j];
  }
}

extern "C" void kernel_launch(void* const* d_in, const int* in_sizes, int n_in,
                              void* d_out, int out_size, void* d_ws, size_t ws_size,
                              hipStream_t stream) {
  const float* x       = (const float*)d_in[0];
  const float* la_w1   = (const float*)d_in[1];
  const float* la_b1   = (const float*)d_in[2];
  const float* la_g1   = (const float*)d_in[3];
  const float* la_be1  = (const float*)d_in[4];
  const float* la_m1   = (const float*)d_in[5];
  const float* la_v1   = (const float*)d_in[6];
  const float* la_w2   = (const float*)d_in[7];
  const float* la_b2   = (const float*)d_in[8];
  const float* la_g2   = (const float*)d_in[9];
  const float* la_be2  = (const float*)d_in[10];
  const float* la_m2   = (const float*)d_in[11];
  const float* la_v2   = (const float*)d_in[12];
  const float* ga_w1   = (const float*)d_in[13];
  const float* ga_b1   = (const float*)d_in[14];
  const float* ga_g1   = (const float*)d_in[15];
  const float* ga_be1  = (const float*)d_in[16];
  const float* ga_m1   = (const float*)d_in[17];
  const float* ga_v1   = (const float*)d_in[18];
  const float* ga_w2   = (const float*)d_in[19];
  const float* ga_b2   = (const float*)d_in[20];
  const float* ga_g2   = (const float*)d_in[21];
  const float* ga_be2  = (const float*)d_in[22];
  const float* ga_m2   = (const float*)d_in[23];
  const float* ga_v2   = (const float*)d_in[24];
  const float* cl_w    = (const float*)d_in[25];
  const float* cl_b    = (const float*)d_in[26];

  float* ws = (float*)d_ws;
  __hip_bfloat16* Gb = (__hip_bfloat16*)((char*)d_ws + OFF_GB_BYTES);
  float* out = (float*)d_out;

  hipMemsetAsync(d_ws, 0, MC_*B_*sizeof(float), stream);   // zero P for atomics
  k_pool  <<<dim3(288, 8), 256, 0, stream>>>(x, ws);
  k_repack<<<649, 256, 0, stream>>>(la_w1, la_b1, la_g1, la_be1, la_m1, la_v1,
                                    la_w2, la_b2, la_g2, la_be2, la_m2, la_v2,
                                    cl_w, ws);
  k_ga    <<<1, 64, 0, stream>>>(ga_w1, ga_b1, ga_g1, ga_be1, ga_m1, ga_v1,
                                 ga_w2, ga_b2, ga_g2, ga_be2, ga_m2, ga_v2, ws);
  k_F     <<<dim3(32, 9, 2), 256, 0, stream>>>(x, ws);
  k_comb1 <<<dim3(128, 2), 576, 0, stream>>>(x, ws);
  k_conv2 <<<dim3(16, 16, 2), 576, 0, stream>>>(ws);
  k_G     <<<dim3(128, 9, 2), 192, 0, stream>>>(x, ws, Gb);
  k_last  <<<dim3(19, 128, 2), 256, 0, stream>>>(ws, Gb, cl_b, out);
}

// Round 8
// 801.955 us; speedup vs baseline: 1.2622x; 1.0417x over previous
//
#include <hip/hip_runtime.h>
#include <hip/hip_bf16.h>
#include <cstddef>

#define B_ 2
#define C_ 16
#define H_ 128
#define W_ 128
#define M_ 9
#define ND_ 9
#define MC_ 144
#define HID_ 18
#define OUT_ 150
#define GOC_ 152          // padded oc stride for G (8B-aligned quads)
#define EPS_ 1e-5f

// ---- workspace layout (float offsets) ----
#define OFF_P     0          // [B][144] pooled means                 (288)
#define OFF_XG    512        // [B][9]  global-attention out          (18)
#define OFF_W1F   1024       // conv1 w, BN1-folded: [mc][kw][kh][kdd][18] (69984)
#define OFF_B1F   71040      // [18]
#define OFF_W2F   71104      // conv2 w, BN2-folded: [c][tap][9]      (4374)
#define OFF_B2F   75520      // [9]
#define OFF_CLWT  75584      // cl_w transposed [mc][150]             (21600)
#define OFF_F     98304      // F'[b][m][kdd][o][h][wpp132]           (16,422,912)
#define FSLAB_    912384     // per-(b,m) slab = 3*18*128*132
#define OFF_HBUF  18069504   // h pre-relu: [b][h][d][w][18]          (5,308,416)
#define OFF_WEI   23377920   // sigmoid attention: [b][h][w][m][d]    (2,654,208)
// W1T: conv1 weights re-laid [m][o][c][tap27] for k_F's scalar loads. It lives
// in the TAIL of the HBUF region: k_repack writes it, k_F reads it, and only
// afterwards does k_comb1 overwrite the region with HBUF. (69,984 floats)
#define OFF_W1T   23307936   // = OFF_WEI - 69984
// G (bf16) overlays F+HBUF: both are dead before k_G runs.
// G[b][h][m][w'][152] = 44,777,472 bf16 = 89.6 MB; ends well before OFF_WEI.
#define OFF_GB_BYTES (98304ull*4ull)

// ---------------- K1: pooled mean of cost volume (global-attn input) ----------
// Split over 8 h-ranges per (b,mc); atomicAdd into P (zeroed by memset).
__global__ __launch_bounds__(256) void k_pool(const float* __restrict__ x,
                                              float* __restrict__ ws) {
  int bid = blockIdx.x;                 // 0..287 = b*144+mc
  int z   = blockIdx.y;                 // 0..7
  int b = bid / MC_, mc = bid % MC_;
  int m = mc / C_, c = mc % C_;
  int sm = m - 4;
  const float* xb = x + (size_t)(b*C_ + c)*H_*W_*M_;
  float acc = 0.f;
  int i0 = z * (H_*W_*ND_/8);
  int i1 = i0 + (H_*W_*ND_/8);
  for (int idx = i0 + (int)threadIdx.x; idx < i1; idx += 256) {
    int w = idx & 127;
    int t = idx >> 7;
    int d = t % 9;
    int h = t / 9;
    int wc = w + (d - 4)*sm;
    if (wc >= 0 && wc < W_) acc += xb[(h*W_ + wc)*M_ + m];
  }
  __shared__ float red[256];
  red[threadIdx.x] = acc;
  __syncthreads();
  for (int s = 128; s > 0; s >>= 1) {
    if ((int)threadIdx.x < s) red[threadIdx.x] += red[threadIdx.x + s];
    __syncthreads();
  }
  if (threadIdx.x == 0)
    atomicAdd(&ws[OFF_P + b*MC_ + mc], red[0] * (1.f/(float)(H_*W_*ND_)));
}

// ---------------- K2: fold BN into conv weights; transpose layouts ------------
__global__ __launch_bounds__(256) void k_repack(
    const float* __restrict__ w1, const float* __restrict__ b1,
    const float* __restrict__ g1, const float* __restrict__ be1,
    const float* __restrict__ m1, const float* __restrict__ v1,
    const float* __restrict__ w2, const float* __restrict__ b2,
    const float* __restrict__ g2, const float* __restrict__ be2,
    const float* __restrict__ m2, const float* __restrict__ v2,
    const float* __restrict__ clw, float* __restrict__ ws) {
  int id = blockIdx.x*256 + threadIdx.x;
  if (id < 69984) {                      // w1f: [mc][kw][kh][kdd][o]
    int o   = id % 18;
    int kdd = (id/18) % 3;
    int kh  = (id/54) % 3;
    int kw  = (id/162) % 3;
    int mc  = id/486;
    float s = g1[o] / sqrtf(v1[o] + EPS_);
    ws[OFF_W1F + id] = w1[(o*MC_ + mc)*27 + kh*9 + kw*3 + kdd] * s;
    return;
  }
  id -= 69984;
  if (id < 18) {
    float s = g1[id]/sqrtf(v1[id]+EPS_);
    ws[OFF_B1F + id] = (b1[id]-m1[id])*s + be1[id];
    return;
  }
  id -= 18;
  if (id < 4374) {                       // w2f: [c][tap][i]
    int i = id % 9, tap = (id/9) % 27, c = id/243;
    float s = g2[i]/sqrtf(v2[i]+EPS_);
    ws[OFF_W2F + id] = w2[(i*HID_ + c)*27 + tap] * s;
    return;
  }
  id -= 4374;
  if (id < 9) {
    float s = g2[id]/sqrtf(v2[id]+EPS_);
    ws[OFF_B2F + id] = (b2[id]-m2[id])*s + be2[id];
    return;
  }
  id -= 9;
  if (id < 21600) {                      // clwT: [mc][oc]
    int oc = id % OUT_, mc = id / OUT_;
    ws[OFF_CLWT + id] = clw[oc*MC_ + mc];
    return;
  }
  id -= 21600;
  if (id < 69984) {                      // W1T: [m][o][c][tap27], tap=kw*9+kh*3+kdd
    int tap = id % 27;
    int kw  = tap / 9;
    int kh  = (tap % 9) / 3;
    int kdd = tap % 3;
    int c   = (id/27) % 16;
    int o   = (id/432) % 18;
    int m   = id / 7776;
    float s = g1[o] / sqrtf(v1[o] + EPS_);
    ws[OFF_W1T + id] = w1[(o*MC_ + m*C_ + c)*27 + kh*9 + kw*3 + kdd] * s;
  }
}

// ---------------- K3: global attention branch (1x1x1 volume => center taps) ---
__global__ __launch_bounds__(64) void k_ga(
    const float* __restrict__ gw1, const float* __restrict__ gb1,
    const float* __restrict__ gg1, const float* __restrict__ gbe1,
    const float* __restrict__ gm1, const float* __restrict__ gv1,
    const float* __restrict__ gw2, const float* __restrict__ gb2,
    const float* __restrict__ gg2, const float* __restrict__ gbe2,
    const float* __restrict__ gm2, const float* __restrict__ gv2,
    float* __restrict__ ws) {
  __shared__ float gl[B_*HID_];
  int t = threadIdx.x;
  if (t < B_*HID_) {
    int b = t / HID_, j = t % HID_;
    float acc = gb1[j];
    for (int ch = 0; ch < MC_; ch++)
      acc += gw1[(j*MC_ + ch)*27 + 13] * ws[OFF_P + b*MC_ + ch];
    float s = gg1[j]/sqrtf(gv1[j]+EPS_);
    gl[t] = fmaxf((acc - gm1[j])*s + gbe1[j], 0.f);
  }
  __syncthreads();
  if (t < B_*M_) {
    int b = t / M_, i = t % M_;
    float acc = gb2[i];
    for (int j = 0; j < HID_; j++)
      acc += gw2[(i*HID_ + j)*27 + 13] * gl[b*HID_ + j];
    float s = gg2[i]/sqrtf(gv2[i]+EPS_);
    ws[OFF_XG + b*M_ + i] = (acc - gm2[i])*s + gbe2[i];
  }
}

// ---------------- K4: F'[b][m][kdd][o][h][wpp] = per-(m,kdd) 2D 3x3 conv of x -
// wave-uniform o, scalar s_load weights from W1T, o-major 256B-contiguous
// wave stores (R6-verified clean writes).
__global__ __launch_bounds__(256) void k_F(const float* __restrict__ x,
                                           float* __restrict__ ws) {
  int h0 = blockIdx.x * 4;
  int m  = blockIdx.y;
  int b  = blockIdx.z;
  const int t = threadIdx.x;
  __shared__ float xt[C_*132*6];        // [c][col 0..131][row 0..5]  50.7 KB
  for (int e = t; e < C_*132*6; e += 256) {
    int hh = e % 6;
    int cc = (e/6) % 132;
    int c  = e / 792;
    int row = h0 - 1 + hh;
    int col = cc - 2;
    float v = 0.f;
    if ((unsigned)row < 128u && (unsigned)col < 128u)
      v = x[(((size_t)(b*C_ + c)*H_ + row)*W_ + col)*M_ + m];
    xt[e] = v;
  }
  __syncthreads();

  const int wave = __builtin_amdgcn_readfirstlane(t >> 6);   // 0..3, SGPR
  const int lane = t & 63;
  const float* w1t = ws + OFF_W1T + (size_t)m*7776;
  float* Fb = ws + OFF_F + (size_t)(b*M_ + m)*FSLAB_;

  for (int oi = 0; oi < 5; oi++) {
    int o = wave + oi*4;                // wave-uniform
    if (o >= 18) break;                 // scalar branch (waves 2,3 do 4 o's)
    float acc[3][4][2];
    #pragma unroll
    for (int kdd = 0; kdd < 3; kdd++)
      #pragma unroll
      for (int hh = 0; hh < 4; hh++) {
        acc[kdd][hh][0] = 0.f; acc[kdd][hh][1] = 0.f;
      }
    for (int c = 0; c < C_; c++) {
      const float* wp = w1t + (o*16 + c)*27;   // uniform addr -> s_load
      float wreg[27];
      #pragma unroll
      for (int i = 0; i < 27; i++) wreg[i] = wp[i];
      #pragma unroll
      for (int wq = 0; wq < 2; wq++) {
        int wpp = wq*64 + lane;
        #pragma unroll
        for (int kw = 0; kw < 3; kw++) {
          const float* xb = &xt[(c*132 + wpp + kw)*6];
          float4 lo = *(const float4*)xb;
          float2 hi = *(const float2*)(xb + 4);
          float xv[6] = {lo.x, lo.y, lo.z, lo.w, hi.x, hi.y};
          #pragma unroll
          for (int kh = 0; kh < 3; kh++)
            #pragma unroll
            for (int kdd = 0; kdd < 3; kdd++) {
              float wv = wreg[kw*9 + kh*3 + kdd];
              #pragma unroll
              for (int hh = 0; hh < 4; hh++)
                acc[kdd][hh][wq] += wv * xv[hh + kh];
            }
        }
      }
    }
    #pragma unroll
    for (int wq = 0; wq < 2; wq++) {
      int wpp = wq*64 + lane;
      #pragma unroll
      for (int kdd = 0; kdd < 3; kdd++)
        #pragma unroll
        for (int hh = 0; hh < 4; hh++)
          Fb[((size_t)(kdd*18 + o)*H_ + (h0+hh))*132 + wpp] = acc[kdd][hh][wq];
    }
  }

  // ---- epilogue: wpp = 128,129 (36 items), small per-lane scatter (~1 MB) ----
  if (t < 36) {
    int o   = t % 18;
    int wpp = 128 + t/18;
    float acc[3][4];
    #pragma unroll
    for (int kdd = 0; kdd < 3; kdd++)
      #pragma unroll
      for (int hh = 0; hh < 4; hh++) acc[kdd][hh] = 0.f;
    for (int c = 0; c < C_; c++) {
      const float* wp = w1t + (o*16 + c)*27;
      #pragma unroll
      for (int kw = 0; kw < 3; kw++) {
        const float* xb = &xt[(c*132 + wpp + kw)*6];
        float4 lo = *(const float4*)xb;
        float2 hi = *(const float2*)(xb + 4);
        float xv[6] = {lo.x, lo.y, lo.z, lo.w, hi.x, hi.y};
        #pragma unroll
        for (int kh = 0; kh < 3; kh++)
          #pragma unroll
          for (int kdd = 0; kdd < 3; kdd++) {
            float wv = wp[kw*9 + kh*3 + kdd];
            #pragma unroll
            for (int hh = 0; hh < 4; hh++)
              acc[kdd][hh] += wv * xv[hh + kh];
          }
      }
    }
    #pragma unroll
    for (int kdd = 0; kdd < 3; kdd++)
      #pragma unroll
      for (int hh = 0; hh < 4; hh++)
        Fb[((size_t)(kdd*18 + o)*H_ + (h0+hh))*132 + wpp] = acc[kdd][hh];
  }
}

// ---------------- K5: conv1 = gather-sum of F' (+edge fix) + BN bias + ReLU ---
#define SLAB21_ 2772          // 132*21 floats per kdd slab in LDS
__global__ __launch_bounds__(576) void k_comb1(const float* __restrict__ x,
                                               float* __restrict__ ws) {
  const int h = blockIdx.x;
  const int b = blockIdx.y;
  const int t = threadIdx.x;
  const int d    = t >> 6;             // wave id 0..8 = output disparity
  const int lane = t & 63;

  __shared__ float fs[3*SLAB21_];      // current-m F rows: [kdd][wpp*21 + o]
  __shared__ float xe[7776];           // [m][edge][dp][kh][c] for edge fix
  __shared__ float corr[9][2][18];

  // ---- staging slots: 1782 float4s = 3 kdd x 18 o x 33 q, over 576 thr ------
  const int iA = t, iB = t + 576, iC = t + 1152;   // < 1728, always valid
  const bool vD = (t < 54);
  const int iD = 1728 + t;
  const int kA = iA/594, rA_ = iA%594, oA = rA_/33, qA = rA_%33;
  const int kB = iB/594, rB_ = iB%594, oB = rB_/33, qB = rB_%33;
  const int kC = iC/594, rC_ = iC%594, oC = rC_/33, qC = rC_%33;
  const int kD = vD ? iD/594 : 0, rD_ = vD ? iD%594 : 0, oD = rD_/33, qD = rD_%33;
  const int gA = ((kA*18 + oA)*H_ + h)*132 + qA*4;
  const int gB = ((kB*18 + oB)*H_ + h)*132 + qB*4;
  const int gC = ((kC*18 + oC)*H_ + h)*132 + qC*4;
  const int gD = ((kD*18 + oD)*H_ + h)*132 + qD*4;
  const int lA = kA*SLAB21_ + qA*84 + oA;
  const int lB = kB*SLAB21_ + qB*84 + oB;
  const int lC = kC*SLAB21_ + qC*84 + oC;
  const int lD = kD*SLAB21_ + qD*84 + oD;

  // prefetch m=0 F rows into regs (latency hidden under xe staging + corr)
  size_t mb = (size_t)OFF_F + (size_t)(b*9 + 0)*FSLAB_;
  float4 rA = *(const float4*)(ws + mb + gA);
  float4 rB = *(const float4*)(ws + mb + gB);
  float4 rC = *(const float4*)(ws + mb + gC);
  float4 rD = vD ? *(const float4*)(ws + mb + gD) : make_float4(0.f,0.f,0.f,0.f);

  // ---- stage x values needed by the edge correction ----
  for (int e = t; e < 7776; e += 576) {
    int c    = e & 15;
    int kh   = (e >> 4) % 3;
    int dp   = (e / 48) % 9;
    int edge = (e / 432) & 1;
    int m    = e / 864;
    int row = h + kh - 1;
    int col = edge ? 128 + (dp - 4)*(m - 4) : (dp - 4)*(m - 4) - 1;
    float v = 0.f;
    if ((unsigned)row < 128u && (unsigned)col < 128u)
      v = x[(((size_t)(b*C_ + c)*H_ + row)*W_ + col)*M_ + m];
    xe[e] = v;
  }
  __syncthreads();

  // ---- cooperative edge correction: 324 threads, one (d,edge,o) each ----
  if (t < 324) {
    int o    = t % 18;
    int edge = (t / 18) & 1;
    int dd   = t / 36;
    int kwe  = edge ? 2 : 0;
    const float* w1b = ws + OFF_W1F + kwe*162 + o;
    float s = 0.f;
    for (int m = 0; m < 9; m++) {
      #pragma unroll
      for (int kdd = 0; kdd < 3; kdd++) {
        int dp = dd + kdd - 1;
        if (dp < 0 || dp >= 9) continue;
        const float* xp = xe + ((m*2 + edge)*9 + dp)*48;   // [kh][c]
        const float* wp = w1b + m*7776 + kdd*18;
        for (int c = 0; c < 16; c++) {
          #pragma unroll
          for (int kh = 0; kh < 3; kh++)
            s += wp[c*486 + kh*54] * xp[kh*16 + c];
        }
      }
    }
    corr[dd][edge][o] = s;
  }

  float acc0[18], acc1[18];
  #pragma unroll
  for (int o = 0; o < 18; o++) {
    float bz = ws[OFF_B1F + o];
    acc0[o] = bz; acc1[o] = bz;
  }

  __syncthreads();                      // corr done; fs safe to fill

  for (int m = 0; m < 9; m++) {
    // commit prefetched regs -> LDS (stride-21 transpose)
    fs[lA+0]=rA.x; fs[lA+21]=rA.y; fs[lA+42]=rA.z; fs[lA+63]=rA.w;
    fs[lB+0]=rB.x; fs[lB+21]=rB.y; fs[lB+42]=rB.z; fs[lB+63]=rB.w;
    fs[lC+0]=rC.x; fs[lC+21]=rC.y; fs[lC+42]=rC.z; fs[lC+63]=rC.w;
    if (vD) { fs[lD+0]=rD.x; fs[lD+21]=rD.y; fs[lD+42]=rD.z; fs[lD+63]=rD.w; }
    // issue next-m loads (hidden under this m's compute)
    if (m < 8) {
      mb = (size_t)OFF_F + (size_t)(b*9 + m + 1)*FSLAB_;
      rA = *(const float4*)(ws + mb + gA);
      rB = *(const float4*)(ws + mb + gB);
      rC = *(const float4*)(ws + mb + gC);
      if (vD) rD = *(const float4*)(ws + mb + gD);
    }
    __syncthreads();

    const int sm = m - 4;
    #pragma unroll
    for (int kdd = 0; kdd < 3; kdd++) {
      int dp = d + kdd - 1;
      if (dp >= 0 && dp < 9) {          // wave-uniform
        int shift = (dp - 4)*sm;
        const float* row_ = fs + kdd*SLAB21_;
        int wg0 = lane + shift;
        if (wg0 >= -1 && wg0 <= 128) {
          const float* p = row_ + (wg0 + 1)*21;
          #pragma unroll
          for (int o = 0; o < 18; o++) acc0[o] += p[o];
        }
        int wg1 = wg0 + 64;
        if (wg1 >= -1 && wg1 <= 128) {
          const float* p = row_ + (wg1 + 1)*21;
          #pragma unroll
          for (int o = 0; o < 18; o++) acc1[o] += p[o];
        }
      }
    }
    __syncthreads();                    // all waves done before fs overwrite
  }

  if (lane == 0) {
    #pragma unroll
    for (int o = 0; o < 18; o++) acc0[o] -= corr[d][0][o];
  }
  if (lane == 63) {
    #pragma unroll
    for (int o = 0; o < 18; o++) acc1[o] -= corr[d][1][o];
  }

  // store with ReLU, layout [b][h][d][w][18]
  float* hb = ws + OFF_HBUF + ((size_t)((b*H_ + h)*ND_ + d)*W_)*18;
  float2* p0 = (float2*)(hb + (size_t)lane*18);
  float2* p1 = (float2*)(hb + (size_t)(lane + 64)*18);
  #pragma unroll
  for (int q = 0; q < 9; q++) {
    p0[q] = make_float2(fmaxf(acc0[2*q], 0.f), fmaxf(acc0[2*q+1], 0.f));
    p1[q] = make_float2(fmaxf(acc1[2*q], 0.f), fmaxf(acc1[2*q+1], 0.f));
  }
}

// ---------------- K6: conv2 (18->9, 3x3x3) + BN + x_g + sigmoid -> wei --------
// wei layout is now [b][h][w][m][d] (m outer) so k_last can batch-load per-m.
__global__ __launch_bounds__(576) void k_conv2(float* __restrict__ ws) {
  int w0 = blockIdx.x * 8;
  int h0 = blockIdx.y * 8;
  int b  = blockIdx.z;
  int t  = threadIdx.x;
  int lh = t / 72;
  int lw = (t / 9) % 8;
  int d  = t % 9;
  __shared__ float ht[9900];            // [hh 10][ww 10][dd 11][cc 9]
  const float* hbuf = ws + OFF_HBUF;
  const float* w2f  = ws + OFF_W2F;
  float acc[9] = {};
  for (int c0 = 0; c0 < 18; c0 += 9) {
    __syncthreads();
    for (int e = t; e < 9900; e += 576) {
      int cc = e % 9;
      int dd = (e/9) % 11;
      int ww = (e/99) % 10;
      int hh = e / 990;
      int gh = h0 - 1 + hh, gw = w0 - 1 + ww, gd = dd - 1;
      float v = 0.f;
      if (gh >= 0 && gh < H_ && gw >= 0 && gw < W_ && gd >= 0 && gd < ND_)
        v = hbuf[(((size_t)(b*H_ + gh)*ND_ + gd)*W_ + gw)*18 + c0 + cc];
      ht[e] = v;
    }
    __syncthreads();
    for (int cc = 0; cc < 9; cc++) {
      #pragma unroll
      for (int kh = 0; kh < 3; kh++)
        #pragma unroll
        for (int kw = 0; kw < 3; kw++)
          #pragma unroll
          for (int kdd = 0; kdd < 3; kdd++) {
            float v = ht[(((lh+kh)*10 + (lw+kw))*11 + (d+kdd))*9 + cc];
            const float* wp = w2f + ((c0+cc)*27 + kh*9 + kw*3 + kdd)*9;
            #pragma unroll
            for (int i = 0; i < 9; i++) acc[i] += wp[i] * v;
          }
    }
  }
  int h = h0 + lh, w = w0 + lw;
  float* wei = ws + OFF_WEI + (size_t)((b*H_ + h)*W_ + w)*81 + d;  // [m][d], d fixed
  const float* xg = ws + OFF_XG + b*M_;
  #pragma unroll
  for (int i = 0; i < 9; i++) {
    float y = acc[i] + ws[OFF_B2F + i] + xg[i];
    wei[i*9] = 1.f / (1.f + expf(-y));
  }
}

// ---------------- K7: G[b][h][m][w'][152] = sum_c clw[oc][mc]*x[c,h,w',m] -----
// x row staged in LDS once; compute with broadcast float4 LDS reads.
__global__ __launch_bounds__(192) void k_G(const float* __restrict__ x,
                                           const float* __restrict__ ws,
                                           __hip_bfloat16* __restrict__ Gb) {
  int h = blockIdx.x, m = blockIdx.y, b = blockIdx.z;
  __shared__ float xs[C_][W_];          // 8 KB
  for (int e = threadIdx.x; e < C_*W_; e += 192) {
    int c = e >> 7, wp = e & 127;
    xs[c][wp] = x[(((size_t)(b*C_ + c)*H_ + h)*W_ + wp)*M_ + m];
  }
  __syncthreads();
  int oc = threadIdx.x;
  if (oc >= GOC_) return;
  __hip_bfloat16* Gr = Gb + ((size_t)(b*H_ + h)*M_ + m)*W_*GOC_;
  if (oc >= OUT_) {                     // zero the pad lanes
    for (int wp = 0; wp < W_; wp++) Gr[wp*GOC_ + oc] = __float2bfloat16(0.f);
    return;
  }
  const float* clwT = ws + OFF_CLWT;
  float wreg[C_];
  #pragma unroll
  for (int c = 0; c < C_; c++) wreg[c] = clwT[(m*C_ + c)*OUT_ + oc];
  for (int wp0 = 0; wp0 < W_; wp0 += 4) {
    float a0 = 0.f, a1 = 0.f, a2 = 0.f, a3 = 0.f;
    #pragma unroll
    for (int c = 0; c < C_; c++) {
      float4 xv = *(const float4*)&xs[c][wp0];
      a0 += wreg[c]*xv.x; a1 += wreg[c]*xv.y;
      a2 += wreg[c]*xv.z; a3 += wreg[c]*xv.w;
    }
    Gr[(wp0+0)*GOC_ + oc] = __float2bfloat16(a0);
    Gr[(wp0+1)*GOC_ + oc] = __float2bfloat16(a1);
    Gr[(wp0+2)*GOC_ + oc] = __float2bfloat16(a2);
    Gr[(wp0+3)*GOC_ + oc] = __float2bfloat16(a3);
  }
}

// ---------------- K8: out = cl_b + sum_m wei[m]*G[h][m][w+s][oc] --------------
// v2: per-m batched loads. All 9 d G-quads + 9 wei floats are issued as
// independent loads BEFORE any FMA consumes them (9-11 loads in flight vs
// v1's serial load->use chain at VGPR=40 -- the measured latency bottleneck:
// VALUBusy 14%, HBM 27%, occ 54%).
__global__ __launch_bounds__(256) void k_last(const float* __restrict__ ws,
                                              const __hip_bfloat16* __restrict__ Gb,
                                              const float* __restrict__ clb,
                                              float* __restrict__ out) {
  int h = blockIdx.y;
  int b = blockIdx.z;
  int idx = blockIdx.x*256 + threadIdx.x;   // 0..4863 = w*38 + ocq
  int w   = idx / 38;
  int ocq = idx % 38;
  int oc0 = ocq * 4;

  float acc[9][4];
  #pragma unroll
  for (int j = 0; j < 4; j++) {
    float cb = (oc0 + j < OUT_) ? clb[oc0 + j] : 0.f;
    #pragma unroll
    for (int d = 0; d < 9; d++) acc[d][j] = cb;
  }

  const float* wv = ws + OFF_WEI + (size_t)((b*H_ + h)*W_ + w)*81;  // [m][d]
  const __hip_bfloat16* Gh = Gb + (size_t)(b*H_ + h)*M_*W_*GOC_;
  for (int m = 0; m < 9; m++) {
    int sm = m - 4;
    const __hip_bfloat16* Gm = Gh + (size_t)m*W_*GOC_;
    // batch-issue all 9 G loads (independent; zero-fill out-of-range)
    ushort4 g[9];
    #pragma unroll
    for (int d = 0; d < 9; d++) {
      int wg = w + (d - 4)*sm;
      g[d] = ((unsigned)wg < (unsigned)W_)
               ? *(const ushort4*)(Gm + wg*GOC_ + oc0)
               : make_ushort4(0, 0, 0, 0);
    }
    // batch-issue the 9 wei floats for this m (contiguous [m][d] row)
    float wm[9];
    #pragma unroll
    for (int d = 0; d < 9; d++) wm[d] = wv[m*9 + d];
    // consume
    #pragma unroll
    for (int d = 0; d < 9; d++) {
      float wf = wm[d];
      acc[d][0] += wf * __uint_as_float(((unsigned)g[d].x) << 16);
      acc[d][1] += wf * __uint_as_float(((unsigned)g[d].y) << 16);
      acc[d][2] += wf * __uint_as_float(((unsigned)g[d].z) << 16);
      acc[d][3] += wf * __uint_as_float(((unsigned)g[d].w) << 16);
    }
  }

  #pragma unroll
  for (int j = 0; j < 4; j++) {
    int oc = oc0 + j;
    if (oc >= OUT_) break;
    float* op = out + (((size_t)(b*OUT_ + oc)*H_ + h)*W_ + w)*9;
    #pragma unroll
    for (int d = 0; d < 9; d++) op[d] = acc[d][j];
  }
}

extern "C" void kernel_launch(void* const* d_in, const int* in_sizes, int n_in,
                              void* d_out, int out_size, void* d_ws, size_t ws_size,
                              hipStream_t stream) {
  const float* x       = (const float*)d_in[0];
  const float* la_w1   = (const float*)d_in[1];
  const float* la_b1   = (const float*)d_in[2];
  const float* la_g1   = (const float*)d_in[3];
  const float* la_be1  = (const float*)d_in[4];
  const float* la_m1   = (const float*)d_in[5];
  const float* la_v1   = (const float*)d_in[6];
  const float* la_w2   = (const float*)d_in[7];
  const float* la_b2   = (const float*)d_in[8];
  const float* la_g2   = (const float*)d_in[9];
  const float* la_be2  = (const float*)d_in[10];
  const float* la_m2   = (const float*)d_in[11];
  const float* la_v2   = (const float*)d_in[12];
  const float* ga_w1   = (const float*)d_in[13];
  const float* ga_b1   = (const float*)d_in[14];
  const float* ga_g1   = (const float*)d_in[15];
  const float* ga_be1  = (const float*)d_in[16];
  const float* ga_m1   = (const float*)d_in[17];
  const float* ga_v1   = (const float*)d_in[18];
  const float* ga_w2   = (const float*)d_in[19];
  const float* ga_b2   = (const float*)d_in[20];
  const float* ga_g2   = (const float*)d_in[21];
  const float* ga_be2  = (const float*)d_in[22];
  const float* ga_m2   = (const float*)d_in[23];
  const float* ga_v2   = (const float*)d_in[24];
  const float* cl_w    = (const float*)d_in[25];
  const float* cl_b    = (const float*)d_in[26];

  float* ws = (float*)d_ws;
  __hip_bfloat16* Gb = (__hip_bfloat16*)((char*)d_ws + OFF_GB_BYTES);
  float* out = (float*)d_out;

  hipMemsetAsync(d_ws, 0, MC_*B_*sizeof(float), stream);   // zero P for atomics
  k_pool  <<<dim3(288, 8), 256, 0, stream>>>(x, ws);
  k_repack<<<649, 256, 0, stream>>>(la_w1, la_b1, la_g1, la_be1, la_m1, la_v1,
                                    la_w2, la_b2, la_g2, la_be2, la_m2, la_v2,
                                    cl_w, ws);
  k_ga    <<<1, 64, 0, stream>>>(ga_w1, ga_b1, ga_g1, ga_be1, ga_m1, ga_v1,
                                 ga_w2, ga_b2, ga_g2, ga_be2, ga_m2, ga_v2, ws);
  k_F     <<<dim3(32, 9, 2), 256, 0, stream>>>(x, ws);
  k_comb1 <<<dim3(128, 2), 576, 0, stream>>>(x, ws);
  k_conv2 <<<dim3(16, 16, 2), 576, 0, stream>>>(ws);
  k_G     <<<dim3(128, 9, 2), 192, 0, stream>>>(x, ws, Gb);
  k_last  <<<dim3(19, 128, 2), 256, 0, stream>>>(ws, Gb, cl_b, out);
}